// Round 5
// baseline (2039.909 us; speedup 1.0000x reference)
//
#include <hip/hip_runtime.h>

// ---------------------------------------------------------------------------
// DecoderBackbone: 4-layer llama-style decoder, B=2 T=1024 HID=2048,
// NH=16 NKV=4 HD=128, INTER=5632. fp32 residual stream, bf16 MFMA GEMMs.
// R5: KV-split flash attention (S=2) + combine; RoPE/V-transpose folded into
// QKV reduce; K-reg prefetch reverted (null, VGPR cost).
// ---------------------------------------------------------------------------

typedef __attribute__((ext_vector_type(8))) __bf16 bf16x8;
typedef __attribute__((ext_vector_type(4))) float f32x4;
typedef __attribute__((ext_vector_type(4))) unsigned short u16x4;

#define DEV __device__ __forceinline__

#define NTOK 2048     // B*T
#define HIDDIM 2048
#define NHEADS 16
#define NKVH 4
#define HDIM 128
#define KVDIM 512     // NKV*HD
#define INTERDIM 5632

DEV unsigned short f2bf(float f) {
  union { float f; unsigned u; } a; a.f = f;
  unsigned r = a.u + 0x7fffu + ((a.u >> 16) & 1u);   // RNE
  return (unsigned short)(r >> 16);
}
DEV float bf2f(unsigned short h) {
  union { unsigned u; float f; } a; a.u = ((unsigned)h) << 16;
  return a.f;
}
DEV void gload_lds16(const void* g, void* l) {
  __builtin_amdgcn_global_load_lds(
      (const __attribute__((address_space(1))) unsigned int*)(g),
      (__attribute__((address_space(3))) unsigned int*)(l), 16, 0, 0);
}

// ---------------------------------------------------------------------------
// fp32 -> bf16 weight convert, 8 elems/thread. n8 = n/8.
// ---------------------------------------------------------------------------
__global__ __launch_bounds__(256) void cvt_kernel(
    const float* __restrict__ in, unsigned short* __restrict__ out, int n8) {
  const int i = blockIdx.x * 256 + threadIdx.x;
  if (i >= n8) return;
  const f32x4* p = reinterpret_cast<const f32x4*>(in) + (size_t)i * 2;
  const f32x4 a = p[0], b = p[1];
  bf16x8 o;
  o[0] = (__bf16)a.x; o[1] = (__bf16)a.y; o[2] = (__bf16)a.z; o[3] = (__bf16)a.w;
  o[4] = (__bf16)b.x; o[5] = (__bf16)b.y; o[6] = (__bf16)b.z; o[7] = (__bf16)b.w;
  *reinterpret_cast<bf16x8*>(out + (size_t)i * 8) = o;
}

// ---------------------------------------------------------------------------
// RMSNorm: x fp32 [row][2048] -> out (bf16 or fp32), one block per row.
// ---------------------------------------------------------------------------
template <int OUTF32>
__global__ __launch_bounds__(256) void rmsnorm_kernel(
    const float* __restrict__ x, const float* __restrict__ w,
    void* __restrict__ outp) {
  const int row = blockIdx.x, tid = threadIdx.x;
  const int lane = tid & 63, wave = tid >> 6;
  const float* xr = x + (size_t)row * HIDDIM;
  f32x4 v0 = *reinterpret_cast<const f32x4*>(xr + tid * 4);
  f32x4 v1 = *reinterpret_cast<const f32x4*>(xr + 1024 + tid * 4);
  float ss = v0.x * v0.x + v0.y * v0.y + v0.z * v0.z + v0.w * v0.w +
             v1.x * v1.x + v1.y * v1.y + v1.z * v1.z + v1.w * v1.w;
#pragma unroll
  for (int off = 1; off < 64; off <<= 1) ss += __shfl_xor(ss, off, 64);
  __shared__ float red[4];
  if (lane == 0) red[wave] = ss;
  __syncthreads();
  ss = red[0] + red[1] + red[2] + red[3];
  const float rs = rsqrtf(ss * (1.0f / 2048.0f) + 1e-6f);
  f32x4 w0 = *reinterpret_cast<const f32x4*>(w + tid * 4);
  f32x4 w1 = *reinterpret_cast<const f32x4*>(w + 1024 + tid * 4);
  if (OUTF32) {
    float* o = (float*)outp + (size_t)row * HIDDIM;
    f32x4 o0, o1;
    o0.x = v0.x * rs * w0.x; o0.y = v0.y * rs * w0.y;
    o0.z = v0.z * rs * w0.z; o0.w = v0.w * rs * w0.w;
    o1.x = v1.x * rs * w1.x; o1.y = v1.y * rs * w1.y;
    o1.z = v1.z * rs * w1.z; o1.w = v1.w * rs * w1.w;
    *reinterpret_cast<f32x4*>(o + tid * 4) = o0;
    *reinterpret_cast<f32x4*>(o + 1024 + tid * 4) = o1;
  } else {
    unsigned short* o = (unsigned short*)outp + (size_t)row * HIDDIM;
    u16x4 p0, p1;
    p0.x = f2bf(v0.x * rs * w0.x); p0.y = f2bf(v0.y * rs * w0.y);
    p0.z = f2bf(v0.z * rs * w0.z); p0.w = f2bf(v0.w * rs * w0.w);
    p1.x = f2bf(v1.x * rs * w1.x); p1.y = f2bf(v1.y * rs * w1.y);
    p1.z = f2bf(v1.z * rs * w1.z); p1.w = f2bf(v1.w * rs * w1.w);
    *reinterpret_cast<u16x4*>(o + tid * 4) = p0;
    *reinterpret_cast<u16x4*>(o + 1024 + tid * 4) = p1;
  }
}

// ---------------------------------------------------------------------------
// 256x256 8-phase GEMM (T2+T3+T4+T5). C = A[M,K] * W[N,K]^T, bf16 in.
// EPI: 0=bf16(+bias), 2=silu(gate)*v bf16, 3=fp32 partial plane.
// ---------------------------------------------------------------------------
template <int MB>
DEV void mfma16(const bf16x8 (&aF)[4], const bf16x8 (&bF)[4],
                f32x4 (&acc)[8][4]) {
#pragma unroll
  for (int ni = 0; ni < 4; ++ni)
#pragma unroll
    for (int mi = 0; mi < 4; ++mi)
      acc[MB + mi][ni] = __builtin_amdgcn_mfma_f32_16x16x32_bf16(
          aF[mi], bF[ni], acc[MB + mi][ni], 0, 0, 0);
}

template <int EPI>
__global__ __launch_bounds__(512, 2) void gemm8p(
    const unsigned short* __restrict__ A, const unsigned short* __restrict__ W,
    const float* __restrict__ bias, unsigned short* __restrict__ outb,
    const unsigned short* __restrict__ gate, float* __restrict__ outf,
    int K, int ldo, int kt_split, int kt_tot, size_t zstride) {
  __shared__ unsigned short lds[65536];   // 128 KiB: [buf2][half4][128*64]
  const int tid = threadIdx.x, lane = tid & 63, wave = tid >> 6;
  const int fr = lane & 15, lq = lane >> 4;
  const int wm = wave >> 2, wn = wave & 3;

  int bx = blockIdx.x, by = blockIdx.y;
  {
    const int nbx = gridDim.x, nwg = nbx * gridDim.y;
    const int lin = by * nbx + bx, cpx = nwg >> 3;
    const int swz = (lin & 7) * cpx + (lin >> 3);
    bx = swz % nbx; by = swz / nbx;
  }
  const int m0 = by * 256, n0 = bx * 256;
  const int bz = blockIdx.z;
  const int t0 = bz * kt_split;
  int NT = kt_tot - t0; if (NT > kt_split) NT = kt_split;

  const int u0 = tid, u1 = tid + 512;
  const int r0s = u0 >> 3, r1s = u1 >> 3;
  const size_t off0 = (size_t)r0s * K + (size_t)((((u0 & 7) ^ (r0s & 7))) << 3);
  const size_t off1 = (size_t)r1s * K + (size_t)((((u1 & 7) ^ (r1s & 7))) << 3);
  const unsigned short* gb0 = A + (size_t)(m0)*K + (size_t)t0 * 64;
  const unsigned short* gb1 = A + (size_t)(m0 + 128) * K + (size_t)t0 * 64;
  const unsigned short* gb2 = W + (size_t)(n0)*K + (size_t)t0 * 64;
  const unsigned short* gb3 = W + (size_t)(n0 + 128) * K + (size_t)t0 * 64;

#define STAGE(h_, tt_, b_)                                                    \
  do {                                                                        \
    const unsigned short* _g =                                                \
        ((h_) == 0 ? gb0 : (h_) == 1 ? gb1 : (h_) == 2 ? gb2 : gb3) +         \
        (size_t)(tt_)*64;                                                     \
    unsigned short* _l = &lds[(b_)*32768 + (h_)*8192 + wave * 512];           \
    gload_lds16(_g + off0, _l);                                               \
    gload_lds16(_g + off1, _l + 4096);                                        \
  } while (0)

  const int e0 = lq ^ (fr & 7);
  const int cbA = wm * 8192;
  const int cbB = (2 + (wn >> 1)) * 8192;
  const int rB0 = (wn & 1) * 64 + fr;

#define LDA(mi_, ks_, c_)                                                     \
  (*reinterpret_cast<const bf16x8*>(                                          \
      &lds[(c_)*32768 + cbA + ((mi_)*16 + fr) * 64 + ((e0 ^ ((ks_)*4)) << 3)]))
#define LDB(ni_, ks_, c_)                                                     \
  (*reinterpret_cast<const bf16x8*>(                                          \
      &lds[(c_)*32768 + cbB + (rB0 + (ni_)*16) * 64 + ((e0 ^ ((ks_)*4)) << 3)]))

#define BARRIER() asm volatile("s_barrier" ::: "memory")

  f32x4 acc[8][4] = {};
  bf16x8 aF[4], bF[4];

  STAGE(0, 0, 0); STAGE(1, 0, 0); STAGE(2, 0, 0); STAGE(3, 0, 0);

  for (int t = 0; t < NT; ++t) {
    const int c = t & 1;
    if (t + 1 < NT) {
      STAGE(0, t + 1, c ^ 1);
      STAGE(2, t + 1, c ^ 1);
      asm volatile("s_waitcnt vmcnt(4)" ::: "memory");
    } else {
      asm volatile("s_waitcnt vmcnt(0)" ::: "memory");
    }
    BARRIER();

    bF[0] = LDB(0, 0, c); bF[1] = LDB(1, 0, c);
    bF[2] = LDB(2, 0, c); bF[3] = LDB(3, 0, c);
    aF[0] = LDA(0, 0, c); aF[1] = LDA(1, 0, c);
    aF[2] = LDA(2, 0, c); aF[3] = LDA(3, 0, c);
    if (t + 1 < NT) { STAGE(1, t + 1, c ^ 1); STAGE(3, t + 1, c ^ 1); }
    BARRIER();
    __builtin_amdgcn_s_setprio(1);
    mfma16<0>(aF, bF, acc);
    __builtin_amdgcn_s_setprio(0);
    __builtin_amdgcn_sched_barrier(0);
    BARRIER();

    aF[0] = LDA(4, 0, c); aF[1] = LDA(5, 0, c);
    aF[2] = LDA(6, 0, c); aF[3] = LDA(7, 0, c);
    BARRIER();
    __builtin_amdgcn_s_setprio(1);
    mfma16<4>(aF, bF, acc);
    __builtin_amdgcn_s_setprio(0);
    __builtin_amdgcn_sched_barrier(0);
    BARRIER();

    bF[0] = LDB(0, 1, c); bF[1] = LDB(1, 1, c);
    bF[2] = LDB(2, 1, c); bF[3] = LDB(3, 1, c);
    aF[0] = LDA(0, 1, c); aF[1] = LDA(1, 1, c);
    aF[2] = LDA(2, 1, c); aF[3] = LDA(3, 1, c);
    BARRIER();
    __builtin_amdgcn_s_setprio(1);
    mfma16<0>(aF, bF, acc);
    __builtin_amdgcn_s_setprio(0);
    __builtin_amdgcn_sched_barrier(0);
    BARRIER();

    aF[0] = LDA(4, 1, c); aF[1] = LDA(5, 1, c);
    aF[2] = LDA(6, 1, c); aF[3] = LDA(7, 1, c);
    BARRIER();
    __builtin_amdgcn_s_setprio(1);
    mfma16<4>(aF, bF, acc);
    __builtin_amdgcn_s_setprio(0);
    __builtin_amdgcn_sched_barrier(0);
    BARRIER();
  }

  const int r0 = lq * 4;
#pragma unroll
  for (int mi = 0; mi < 8; ++mi)
#pragma unroll
    for (int ni = 0; ni < 4; ++ni)
#pragma unroll
      for (int r = 0; r < 4; ++r) {
        const int gm = m0 + wm * 128 + mi * 16 + r0 + r;
        const int gn = n0 + wn * 64 + ni * 16 + fr;
        const float v = acc[mi][ni][r];
        if (EPI == 0) {
          float vv = v;
          if (bias) vv += bias[gn];
          outb[(size_t)gm * ldo + gn] = f2bf(vv);
        } else if (EPI == 2) {
          const float g = bf2f(gate[(size_t)gm * ldo + gn]);
          const float s = g / (1.f + __expf(-g));
          outb[(size_t)gm * ldo + gn] = f2bf(s * v);
        } else {
          outf[(size_t)bz * zstride + (size_t)gm * ldo + gn] = v;
        }
      }
#undef STAGE
#undef LDA
#undef LDB
#undef BARRIER
}

// x[i] += sum_{s<ks} p[s*zs4*4 + i]
__global__ __launch_bounds__(256) void reduce_addk(
    float* __restrict__ x, const float* __restrict__ p, int n4, int ks,
    size_t zs4) {
  const f32x4* pv = reinterpret_cast<const f32x4*>(p);
  f32x4* xv = reinterpret_cast<f32x4*>(x);
  for (int i = blockIdx.x * 256 + threadIdx.x; i < n4; i += gridDim.x * 256) {
    f32x4 s = pv[i];
    for (int sp = 1; sp < ks; ++sp) s += pv[(size_t)sp * zs4 + i];
    xv[i] += s;
  }
}

// ---------------------------------------------------------------------------
// QKV split-K2 reduce + bias + RoPE + V-transpose, all fused.
// p: 2 partial planes [2048][3072] fp32. Writes q (roped bf16 [2048][2048]),
// k (roped bf16 [2048][512]), vt (bf16 [(b*4+kvh)*128+d][1024]).
// ---------------------------------------------------------------------------
__global__ __launch_bounds__(256) void reduce_qkv(
    const float* __restrict__ p, const float* __restrict__ qb,
    const float* __restrict__ kb, const float* __restrict__ vb,
    const float* __restrict__ cosb, const float* __restrict__ sinb,
    unsigned short* __restrict__ qo, unsigned short* __restrict__ ko,
    unsigned short* __restrict__ vto) {
  const int i = blockIdx.x * 256 + threadIdx.x;   // < 1,572,864
  const int row = i / 768, c4 = (i - row * 768) * 4;
  const float* p0 = p + (size_t)row * 3072;
  const float* p1 = p + 6291456 + (size_t)row * 3072;
  const f32x4 s = *reinterpret_cast<const f32x4*>(p0 + c4) +
                  *reinterpret_cast<const f32x4*>(p1 + c4);
  if (c4 < 2560) {
    // q or k: bias + rope
    const float* bias; unsigned short* out; int d, ldo;
    if (c4 < 2048) { bias = qb; out = qo; d = c4;        ldo = HIDDIM; }
    else           { bias = kb; out = ko; d = c4 - 2048; ldo = KVDIM; }
    const int dd = d & 127;
    const bool lohalf = (dd < 64);
    const int pc = lohalf ? c4 + 64 : c4 - 64;
    const int pd = lohalf ? d + 64 : d - 64;
    const f32x4 sp = *reinterpret_cast<const f32x4*>(p0 + pc) +
                     *reinterpret_cast<const f32x4*>(p1 + pc);
    const f32x4 bv = *reinterpret_cast<const f32x4*>(bias + d);
    const f32x4 bp = *reinterpret_cast<const f32x4*>(bias + pd);
    const f32x4 cv = *reinterpret_cast<const f32x4*>(cosb + (size_t)row * 128 + dd);
    const f32x4 sv = *reinterpret_cast<const f32x4*>(sinb + (size_t)row * 128 + dd);
    const f32x4 xv = s + bv, pv = sp + bp;
    f32x4 o;
    if (lohalf) o = xv * cv - pv * sv;
    else        o = xv * cv + pv * sv;
    u16x4 ob;
    ob.x = f2bf(o.x); ob.y = f2bf(o.y); ob.z = f2bf(o.z); ob.w = f2bf(o.w);
    *reinterpret_cast<u16x4*>(out + (size_t)row * ldo + d) = ob;
  } else {
    // v: bias, write transposed
    const int d = c4 - 2560;                 // 0..511, 4-aligned
    const int kvh = d >> 7, dd = d & 127;
    const int b = row >> 10, t = row & 1023;
    const f32x4 bv = *reinterpret_cast<const f32x4*>(vb + d);
    const f32x4 o = s + bv;
    unsigned short* vr =
        vto + ((size_t)(b * 4 + kvh) * 128 + dd) * 1024 + t;
    vr[0] = f2bf(o.x); vr[1024] = f2bf(o.y);
    vr[2048] = f2bf(o.z); vr[3072] = f2bf(o.w);
  }
}

// ---------------------------------------------------------------------------
// Flash attention, causal, GQA, KV-SPLIT (S=2). Block = 4 waves; wave owns
// 16 q-rows. z = s*2 + b; split s covers kb in [lo,hi) of [0, qt].
// Writes UNNORMALIZED partials: obuf fp32 [z][h][1024 rows][128], ml (m,l).
// ---------------------------------------------------------------------------
__global__ __launch_bounds__(256) void attn_kernel(
    const unsigned short* __restrict__ q, const unsigned short* __restrict__ k,
    const unsigned short* __restrict__ vt, float* __restrict__ obuf,
    float* __restrict__ ml) {
  __shared__ unsigned short P_lds[4][1024];
  const int tid = threadIdx.x, lane = tid & 63, wave = tid >> 6;
  const int qt = blockIdx.x, h = blockIdx.y, z = blockIdx.z;
  const int b = z & 1, s = z >> 1;
  const int kvh = h >> 2;
  const int q0 = qt * 64 + wave * 16;
  const int tokbase = b * 1024;
  const int fr = lane & 15, kq = (lane >> 4) * 8, r0 = (lane >> 4) * 4;

  bf16x8 aQ[4];
  {
    const unsigned short* qp =
        q + (size_t)(tokbase + q0 + fr) * HIDDIM + h * HDIM + kq;
#pragma unroll
    for (int ds = 0; ds < 4; ++ds)
      aQ[ds] = *reinterpret_cast<const bf16x8*>(qp + ds * 32);
  }
  float mrow[4], lrow[4];
#pragma unroll
  for (int r = 0; r < 4; ++r) { mrow[r] = -1e30f; lrow[r] = 0.f; }
  f32x4 accO[8] = {};
  const float scale = 0.08838834764831845f;
  const unsigned short* kbase = k + (size_t)tokbase * KVDIM + kvh * HDIM;
  const unsigned short* vbase = vt + (size_t)(b * 4 + kvh) * 128 * 1024;
  unsigned short* pw = &P_lds[wave][0];

  const int nh = (qt + 1) >> 1;
  const int lo = s ? nh : 0;
  const int hi = s ? (qt + 1) : nh;

  for (int kb = lo; kb < hi; ++kb) {
    const int kv0 = kb * 64;
    f32x4 sacc[4] = {};
    const unsigned short* kbp = kbase + (size_t)kv0 * KVDIM;
#pragma unroll
    for (int cb = 0; cb < 4; ++cb) {
      const unsigned short* kr = kbp + (size_t)(cb * 16 + fr) * KVDIM + kq;
#pragma unroll
      for (int ds = 0; ds < 4; ++ds) {
        bf16x8 bK = *reinterpret_cast<const bf16x8*>(kr + ds * 32);
        sacc[cb] =
            __builtin_amdgcn_mfma_f32_16x16x32_bf16(aQ[ds], bK, sacc[cb], 0, 0, 0);
      }
    }
    const bool maskblk = (kb == qt);
    float p[4][4];
#pragma unroll
    for (int r = 0; r < 4; ++r) {
      const int grow = q0 + r0 + r;
      float mx = -1e30f;
#pragma unroll
      for (int cb = 0; cb < 4; ++cb) {
        float sv = sacc[cb][r] * scale;
        if (maskblk && (kv0 + cb * 16 + fr > grow)) sv = -1e30f;
        p[cb][r] = sv;
        mx = fmaxf(mx, sv);
      }
#pragma unroll
      for (int off = 1; off < 16; off <<= 1)
        mx = fmaxf(mx, __shfl_xor(mx, off, 64));
      const float mn = fmaxf(mrow[r], mx);
      const float alpha = __expf(mrow[r] - mn);
      float sum = 0.f;
#pragma unroll
      for (int cb = 0; cb < 4; ++cb) {
        const float e = __expf(p[cb][r] - mn);
        p[cb][r] = e; sum += e;
      }
#pragma unroll
      for (int off = 1; off < 16; off <<= 1) sum += __shfl_xor(sum, off, 64);
      lrow[r] = lrow[r] * alpha + sum;
      mrow[r] = mn;
#pragma unroll
      for (int db = 0; db < 8; ++db) accO[db][r] *= alpha;
    }
#pragma unroll
    for (int cb = 0; cb < 4; ++cb)
#pragma unroll
      for (int r = 0; r < 4; ++r)
        pw[(r0 + r) * 64 + cb * 16 + fr] = f2bf(p[cb][r]);
    bf16x8 aP[2];
#pragma unroll
    for (int s2 = 0; s2 < 2; ++s2)
      aP[s2] = *reinterpret_cast<const bf16x8*>(pw + fr * 64 + s2 * 32 + kq);
#pragma unroll
    for (int db = 0; db < 8; ++db) {
      const unsigned short* vr = vbase + (size_t)(db * 16 + fr) * 1024 + kv0 + kq;
#pragma unroll
      for (int s2 = 0; s2 < 2; ++s2) {
        bf16x8 bV = *reinterpret_cast<const bf16x8*>(vr + s2 * 32);
        accO[db] =
            __builtin_amdgcn_mfma_f32_16x16x32_bf16(aP[s2], bV, accO[db], 0, 0, 0);
      }
    }
  }

  // write unnormalized partials
  const size_t prb = ((size_t)z * 16 + h) * 1024 + q0;
#pragma unroll
  for (int db = 0; db < 8; ++db)
#pragma unroll
    for (int r = 0; r < 4; ++r)
      obuf[(prb + r0 + r) * 128 + db * 16 + fr] = accO[db][r];
  if (fr == 0) {
#pragma unroll
    for (int r = 0; r < 4; ++r) {
      ml[(prb + r0 + r) * 2] = mrow[r];
      ml[(prb + r0 + r) * 2 + 1] = lrow[r];
    }
  }
}

// Combine 2 KV-split partials -> normalized bf16 ao. 32 threads per row.
__global__ __launch_bounds__(256) void attn_combine(
    const float* __restrict__ obuf, const float* __restrict__ ml,
    unsigned short* __restrict__ ao) {
  const int idx = blockIdx.x * 256 + threadIdx.x;
  const int row = idx >> 5;              // < 32768
  const int c4 = (idx & 31) * 4;
  const int b = row >> 14, h = (row >> 10) & 15, t = row & 1023;
  const size_t pr0 = ((size_t)(b)*16 + h) * 1024 + t;        // z = b   (s=0)
  const size_t pr1 = ((size_t)(2 + b) * 16 + h) * 1024 + t;  // z = 2+b (s=1)
  const float m0 = ml[pr0 * 2], l0 = ml[pr0 * 2 + 1];
  const float m1 = ml[pr1 * 2], l1 = ml[pr1 * 2 + 1];
  const float M = fmaxf(m0, m1);
  const float w0 = __expf(m0 - M), w1 = __expf(m1 - M);
  const float inv = 1.f / (l0 * w0 + l1 * w1);
  const f32x4 o0 = *reinterpret_cast<const f32x4*>(obuf + pr0 * 128 + c4);
  const f32x4 o1 = *reinterpret_cast<const f32x4*>(obuf + pr1 * 128 + c4);
  const f32x4 o = (o0 * w0 + o1 * w1) * inv;
  u16x4 ob;
  ob.x = f2bf(o.x); ob.y = f2bf(o.y); ob.z = f2bf(o.z); ob.w = f2bf(o.w);
  *reinterpret_cast<u16x4*>(
      ao + (size_t)(b * 1024 + t) * HIDDIM + h * HDIM + c4) = ob;
}

// ---------------------------------------------------------------------------
extern "C" void kernel_launch(void* const* d_in, const int* in_sizes, int n_in,
                              void* d_out, int out_size, void* d_ws,
                              size_t ws_size, hipStream_t stream) {
  (void)in_sizes; (void)n_in; (void)out_size; (void)ws_size;
  const float* hidden = (const float*)d_in[0];
  const float* cosb  = (const float*)d_in[1];
  const float* sinb  = (const float*)d_in[2];
  const float* qw    = (const float*)d_in[3];
  const float* qbias = (const float*)d_in[4];
  const float* kw    = (const float*)d_in[5];
  const float* kbias = (const float*)d_in[6];
  const float* vw    = (const float*)d_in[7];
  const float* vbias = (const float*)d_in[8];
  const float* ow    = (const float*)d_in[9];
  const float* gw    = (const float*)d_in[10];
  const float* uw    = (const float*)d_in[11];
  const float* dw    = (const float*)d_in[12];
  const float* ln1   = (const float*)d_in[13];
  const float* ln2   = (const float*)d_in[14];
  const float* normw = (const float*)d_in[15];

  char* ws = (char*)d_ws;
  float* x               = (float*)ws;                          // 16,777,216 B
  unsigned short* hbuf   = (unsigned short*)(ws + 16777216);    //  8,388,608
  unsigned short* qbuf   = (unsigned short*)(ws + 25165824);    //  8,388,608
  unsigned short* kbuf   = (unsigned short*)(ws + 33554432);    //  2,097,152
  unsigned short* vtbuf  = (unsigned short*)(ws + 35651584);    //  2,097,152
  unsigned short* aobuf  = (unsigned short*)(ws + 39845888);    //  8,388,608
  unsigned short* gatebuf= (unsigned short*)(ws + 48234496);    // 23,068,672
  unsigned short* actbuf = (unsigned short*)(ws + 71303168);    // 23,068,672
  unsigned short* wcvt   = (unsigned short*)(ws + 94371840);    // 23,068,672
  // total: 117,440,512 bytes
  //
  // fp32 partial scratch, all in regions dead at time-of-use:
  //  - pbufQKV (50.3 MB) at 37748736: gap+aobuf+gatebuf+actbuf-head, dead
  //    during QKV gemm (read by reduce_qkv before anything else writes).
  float* pbufQKV = (float*)(ws + 37748736);
  //  - attn partials: obuf 33.5 MB over gatebuf+actbuf-head (dead in attn),
  //    ml 0.5 MB in wcvt head (qkv weights dead post-GEMM).
  float* obufA = (float*)(ws + 48234496);
  float* mlA   = (float*)(ws + 94371840);
  //  - pbufO (33.5 MB) at gatebuf (dead during O-proj).
  float* pbufO = (float*)(ws + 48234496);
  //  - pbufD (50.3 MB) at hbuf..gatebuf (dead during down).
  float* pbufD = (float*)(ws + 16777216);

  unsigned short* wq16 = wcvt;                 // [3072][2048] bf16
  unsigned short* wk16 = wcvt + 4194304;
  unsigned short* wv16 = wcvt + 5242880;

  hipMemcpyAsync(x, hidden, (size_t)NTOK * HIDDIM * 4,
                 hipMemcpyDeviceToDevice, stream);

  for (int l = 0; l < 4; ++l) {
    const float* qw_l = qw + (size_t)l * 2048 * 2048;
    const float* qb_l = qbias + (size_t)l * 2048;
    const float* kw_l = kw + (size_t)l * 512 * 2048;
    const float* kb_l = kbias + (size_t)l * 512;
    const float* vw_l = vw + (size_t)l * 512 * 2048;
    const float* vb_l = vbias + (size_t)l * 512;
    const float* ow_l = ow + (size_t)l * 2048 * 2048;
    const float* gw_l = gw + (size_t)l * 5632 * 2048;
    const float* uw_l = uw + (size_t)l * 5632 * 2048;
    const float* dw_l = dw + (size_t)l * 2048 * 5632;

    rmsnorm_kernel<0><<<NTOK, 256, 0, stream>>>(x, ln1 + l * 2048, hbuf);
    cvt_kernel<<<2048, 256, 0, stream>>>(qw_l, wq16, 524288);
    cvt_kernel<<<512, 256, 0, stream>>>(kw_l, wk16, 131072);
    cvt_kernel<<<512, 256, 0, stream>>>(vw_l, wv16, 131072);
    // fused QKV: [2048,2048] x [3072,2048]^T, split-K2 8-phase
    gemm8p<3><<<dim3(12, 8, 2), 512, 0, stream>>>(
        hbuf, wcvt, nullptr, nullptr, nullptr, pbufQKV, 2048, 3072, 16, 32,
        (size_t)6291456);
    // reduce + bias + rope + v-transpose
    reduce_qkv<<<6144, 256, 0, stream>>>(pbufQKV, qb_l, kb_l, vb_l, cosb,
                                         sinb, qbuf, kbuf, vtbuf);
    // KV-split flash attention + combine
    attn_kernel<<<dim3(16, 16, 4), 256, 0, stream>>>(qbuf, kbuf, vtbuf,
                                                     obufA, mlA);
    attn_combine<<<4096, 256, 0, stream>>>(obufA, mlA, aobuf);

    // O-proj: split-K2 8-phase -> fp32 partials -> x += sum
    cvt_kernel<<<2048, 256, 0, stream>>>(ow_l, wcvt, 524288);
    gemm8p<3><<<dim3(8, 8, 2), 512, 0, stream>>>(
        aobuf, wcvt, nullptr, nullptr, nullptr, pbufO, 2048, 2048, 16, 32,
        (size_t)4194304);
    reduce_addk<<<2048, 256, 0, stream>>>(x, pbufO, 1048576, 2,
                                          (size_t)1048576);

    rmsnorm_kernel<0><<<NTOK, 256, 0, stream>>>(x, ln2 + l * 2048, hbuf);

    // gate
    cvt_kernel<<<5632, 256, 0, stream>>>(gw_l, wcvt, 1441792);
    gemm8p<0><<<dim3(22, 8, 1), 512, 0, stream>>>(
        hbuf, wcvt, nullptr, gatebuf, nullptr, nullptr, 2048, 5632, 32, 32,
        (size_t)0);
    // up (+ silu(gate) epilogue)
    cvt_kernel<<<5632, 256, 0, stream>>>(uw_l, wcvt, 1441792);
    gemm8p<2><<<dim3(22, 8, 1), 512, 0, stream>>>(
        hbuf, wcvt, nullptr, actbuf, gatebuf, nullptr, 2048, 5632, 32, 32,
        (size_t)0);
    // down: split-K3 -> fp32 partials -> x += sum
    cvt_kernel<<<5632, 256, 0, stream>>>(dw_l, wcvt, 1441792);
    gemm8p<3><<<dim3(8, 8, 3), 512, 0, stream>>>(
        actbuf, wcvt, nullptr, nullptr, nullptr, pbufD, 5632, 2048, 30, 88,
        (size_t)4194304);
    reduce_addk<<<2048, 256, 0, stream>>>(x, pbufD, 1048576, 3,
                                          (size_t)1048576);
  }
  rmsnorm_kernel<1><<<NTOK, 256, 0, stream>>>(x, normw, d_out);
}

// Round 6
// 1791.287 us; speedup vs baseline: 1.1388x; 1.1388x over previous
//
#include <hip/hip_runtime.h>

// ---------------------------------------------------------------------------
// DecoderBackbone: 4-layer llama-style decoder, B=2 T=1024 HID=2048,
// NH=16 NKV=4 HD=128, INTER=5632. fp32 residual stream, bf16 MFMA GEMMs.
// R6: attention rebuilt as 3 GEMM-regime kernels: causal-skip QK^T 8-phase
// GEMM (f16 S), row-softmax (in-place S->P bf16), PV GEMM (BM256/BN64).
// Flash/KV-split/combine machinery removed.
// ---------------------------------------------------------------------------

typedef __attribute__((ext_vector_type(8))) __bf16 bf16x8;
typedef __attribute__((ext_vector_type(4))) float f32x4;
typedef __attribute__((ext_vector_type(4))) unsigned short u16x4;

#define DEV __device__ __forceinline__

#define NTOK 2048     // B*T
#define HIDDIM 2048
#define NHEADS 16
#define NKVH 4
#define HDIM 128
#define KVDIM 512     // NKV*HD
#define INTERDIM 5632

DEV unsigned short f2bf(float f) {
  union { float f; unsigned u; } a; a.f = f;
  unsigned r = a.u + 0x7fffu + ((a.u >> 16) & 1u);   // RNE
  return (unsigned short)(r >> 16);
}
DEV float bf2f(unsigned short h) {
  union { unsigned u; float f; } a; a.u = ((unsigned)h) << 16;
  return a.f;
}
DEV unsigned short f2h(float f) {
  union { _Float16 h; unsigned short u; } c; c.h = (_Float16)f; return c.u;
}
DEV float h2f(unsigned short u) {
  union { unsigned short u; _Float16 h; } c; c.u = u; return (float)c.h;
}
DEV void gload_lds16(const void* g, void* l) {
  __builtin_amdgcn_global_load_lds(
      (const __attribute__((address_space(1))) unsigned int*)(g),
      (__attribute__((address_space(3))) unsigned int*)(l), 16, 0, 0);
}

// ---------------------------------------------------------------------------
// fp32 -> bf16 weight convert, 8 elems/thread. n8 = n/8.
// ---------------------------------------------------------------------------
__global__ __launch_bounds__(256) void cvt_kernel(
    const float* __restrict__ in, unsigned short* __restrict__ out, int n8) {
  const int i = blockIdx.x * 256 + threadIdx.x;
  if (i >= n8) return;
  const f32x4* p = reinterpret_cast<const f32x4*>(in) + (size_t)i * 2;
  const f32x4 a = p[0], b = p[1];
  bf16x8 o;
  o[0] = (__bf16)a.x; o[1] = (__bf16)a.y; o[2] = (__bf16)a.z; o[3] = (__bf16)a.w;
  o[4] = (__bf16)b.x; o[5] = (__bf16)b.y; o[6] = (__bf16)b.z; o[7] = (__bf16)b.w;
  *reinterpret_cast<bf16x8*>(out + (size_t)i * 8) = o;
}

// ---------------------------------------------------------------------------
// RMSNorm: x fp32 [row][2048] -> out (bf16 or fp32), one block per row.
// ---------------------------------------------------------------------------
template <int OUTF32>
__global__ __launch_bounds__(256) void rmsnorm_kernel(
    const float* __restrict__ x, const float* __restrict__ w,
    void* __restrict__ outp) {
  const int row = blockIdx.x, tid = threadIdx.x;
  const int lane = tid & 63, wave = tid >> 6;
  const float* xr = x + (size_t)row * HIDDIM;
  f32x4 v0 = *reinterpret_cast<const f32x4*>(xr + tid * 4);
  f32x4 v1 = *reinterpret_cast<const f32x4*>(xr + 1024 + tid * 4);
  float ss = v0.x * v0.x + v0.y * v0.y + v0.z * v0.z + v0.w * v0.w +
             v1.x * v1.x + v1.y * v1.y + v1.z * v1.z + v1.w * v1.w;
#pragma unroll
  for (int off = 1; off < 64; off <<= 1) ss += __shfl_xor(ss, off, 64);
  __shared__ float red[4];
  if (lane == 0) red[wave] = ss;
  __syncthreads();
  ss = red[0] + red[1] + red[2] + red[3];
  const float rs = rsqrtf(ss * (1.0f / 2048.0f) + 1e-6f);
  f32x4 w0 = *reinterpret_cast<const f32x4*>(w + tid * 4);
  f32x4 w1 = *reinterpret_cast<const f32x4*>(w + 1024 + tid * 4);
  if (OUTF32) {
    float* o = (float*)outp + (size_t)row * HIDDIM;
    f32x4 o0, o1;
    o0.x = v0.x * rs * w0.x; o0.y = v0.y * rs * w0.y;
    o0.z = v0.z * rs * w0.z; o0.w = v0.w * rs * w0.w;
    o1.x = v1.x * rs * w1.x; o1.y = v1.y * rs * w1.y;
    o1.z = v1.z * rs * w1.z; o1.w = v1.w * rs * w1.w;
    *reinterpret_cast<f32x4*>(o + tid * 4) = o0;
    *reinterpret_cast<f32x4*>(o + 1024 + tid * 4) = o1;
  } else {
    unsigned short* o = (unsigned short*)outp + (size_t)row * HIDDIM;
    u16x4 p0, p1;
    p0.x = f2bf(v0.x * rs * w0.x); p0.y = f2bf(v0.y * rs * w0.y);
    p0.z = f2bf(v0.z * rs * w0.z); p0.w = f2bf(v0.w * rs * w0.w);
    p1.x = f2bf(v1.x * rs * w1.x); p1.y = f2bf(v1.y * rs * w1.y);
    p1.z = f2bf(v1.z * rs * w1.z); p1.w = f2bf(v1.w * rs * w1.w);
    *reinterpret_cast<u16x4*>(o + tid * 4) = p0;
    *reinterpret_cast<u16x4*>(o + 1024 + tid * 4) = p1;
  }
}

// ---------------------------------------------------------------------------
// 256x256 8-phase GEMM (T2+T3+T4+T5). C = A[M,K] * W[N,K]^T, bf16 in.
// EPI: 0=bf16(+bias), 2=silu(gate)*v bf16, 3=fp32 partial plane.
// ---------------------------------------------------------------------------
template <int MB>
DEV void mfma16(const bf16x8 (&aF)[4], const bf16x8 (&bF)[4],
                f32x4 (&acc)[8][4]) {
#pragma unroll
  for (int ni = 0; ni < 4; ++ni)
#pragma unroll
    for (int mi = 0; mi < 4; ++mi)
      acc[MB + mi][ni] = __builtin_amdgcn_mfma_f32_16x16x32_bf16(
          aF[mi], bF[ni], acc[MB + mi][ni], 0, 0, 0);
}

template <int EPI>
__global__ __launch_bounds__(512, 2) void gemm8p(
    const unsigned short* __restrict__ A, const unsigned short* __restrict__ W,
    const float* __restrict__ bias, unsigned short* __restrict__ outb,
    const unsigned short* __restrict__ gate, float* __restrict__ outf,
    int K, int ldo, int kt_split, int kt_tot, size_t zstride) {
  __shared__ unsigned short lds[65536];   // 128 KiB: [buf2][half4][128*64]
  const int tid = threadIdx.x, lane = tid & 63, wave = tid >> 6;
  const int fr = lane & 15, lq = lane >> 4;
  const int wm = wave >> 2, wn = wave & 3;

  int bx = blockIdx.x, by = blockIdx.y;
  {
    const int nbx = gridDim.x, nwg = nbx * gridDim.y;
    const int lin = by * nbx + bx, cpx = nwg >> 3;
    const int swz = (lin & 7) * cpx + (lin >> 3);
    bx = swz % nbx; by = swz / nbx;
  }
  const int m0 = by * 256, n0 = bx * 256;
  const int bz = blockIdx.z;
  const int t0 = bz * kt_split;
  int NT = kt_tot - t0; if (NT > kt_split) NT = kt_split;

  const int u0 = tid, u1 = tid + 512;
  const int r0s = u0 >> 3, r1s = u1 >> 3;
  const size_t off0 = (size_t)r0s * K + (size_t)((((u0 & 7) ^ (r0s & 7))) << 3);
  const size_t off1 = (size_t)r1s * K + (size_t)((((u1 & 7) ^ (r1s & 7))) << 3);
  const unsigned short* gb0 = A + (size_t)(m0)*K + (size_t)t0 * 64;
  const unsigned short* gb1 = A + (size_t)(m0 + 128) * K + (size_t)t0 * 64;
  const unsigned short* gb2 = W + (size_t)(n0)*K + (size_t)t0 * 64;
  const unsigned short* gb3 = W + (size_t)(n0 + 128) * K + (size_t)t0 * 64;

#define STAGE(h_, tt_, b_)                                                    \
  do {                                                                        \
    const unsigned short* _g =                                                \
        ((h_) == 0 ? gb0 : (h_) == 1 ? gb1 : (h_) == 2 ? gb2 : gb3) +         \
        (size_t)(tt_)*64;                                                     \
    unsigned short* _l = &lds[(b_)*32768 + (h_)*8192 + wave * 512];           \
    gload_lds16(_g + off0, _l);                                               \
    gload_lds16(_g + off1, _l + 4096);                                        \
  } while (0)

  const int e0 = lq ^ (fr & 7);
  const int cbA = wm * 8192;
  const int cbB = (2 + (wn >> 1)) * 8192;
  const int rB0 = (wn & 1) * 64 + fr;

#define LDA(mi_, ks_, c_)                                                     \
  (*reinterpret_cast<const bf16x8*>(                                          \
      &lds[(c_)*32768 + cbA + ((mi_)*16 + fr) * 64 + ((e0 ^ ((ks_)*4)) << 3)]))
#define LDB(ni_, ks_, c_)                                                     \
  (*reinterpret_cast<const bf16x8*>(                                          \
      &lds[(c_)*32768 + cbB + (rB0 + (ni_)*16) * 64 + ((e0 ^ ((ks_)*4)) << 3)]))

#define BARRIER() asm volatile("s_barrier" ::: "memory")

  f32x4 acc[8][4] = {};
  bf16x8 aF[4], bF[4];

  STAGE(0, 0, 0); STAGE(1, 0, 0); STAGE(2, 0, 0); STAGE(3, 0, 0);

  for (int t = 0; t < NT; ++t) {
    const int c = t & 1;
    if (t + 1 < NT) {
      STAGE(0, t + 1, c ^ 1);
      STAGE(2, t + 1, c ^ 1);
      asm volatile("s_waitcnt vmcnt(4)" ::: "memory");
    } else {
      asm volatile("s_waitcnt vmcnt(0)" ::: "memory");
    }
    BARRIER();

    bF[0] = LDB(0, 0, c); bF[1] = LDB(1, 0, c);
    bF[2] = LDB(2, 0, c); bF[3] = LDB(3, 0, c);
    aF[0] = LDA(0, 0, c); aF[1] = LDA(1, 0, c);
    aF[2] = LDA(2, 0, c); aF[3] = LDA(3, 0, c);
    if (t + 1 < NT) { STAGE(1, t + 1, c ^ 1); STAGE(3, t + 1, c ^ 1); }
    BARRIER();
    __builtin_amdgcn_s_setprio(1);
    mfma16<0>(aF, bF, acc);
    __builtin_amdgcn_s_setprio(0);
    __builtin_amdgcn_sched_barrier(0);
    BARRIER();

    aF[0] = LDA(4, 0, c); aF[1] = LDA(5, 0, c);
    aF[2] = LDA(6, 0, c); aF[3] = LDA(7, 0, c);
    BARRIER();
    __builtin_amdgcn_s_setprio(1);
    mfma16<4>(aF, bF, acc);
    __builtin_amdgcn_s_setprio(0);
    __builtin_amdgcn_sched_barrier(0);
    BARRIER();

    bF[0] = LDB(0, 1, c); bF[1] = LDB(1, 1, c);
    bF[2] = LDB(2, 1, c); bF[3] = LDB(3, 1, c);
    aF[0] = LDA(0, 1, c); aF[1] = LDA(1, 1, c);
    aF[2] = LDA(2, 1, c); aF[3] = LDA(3, 1, c);
    BARRIER();
    __builtin_amdgcn_s_setprio(1);
    mfma16<0>(aF, bF, acc);
    __builtin_amdgcn_s_setprio(0);
    __builtin_amdgcn_sched_barrier(0);
    BARRIER();

    aF[0] = LDA(4, 1, c); aF[1] = LDA(5, 1, c);
    aF[2] = LDA(6, 1, c); aF[3] = LDA(7, 1, c);
    BARRIER();
    __builtin_amdgcn_s_setprio(1);
    mfma16<4>(aF, bF, acc);
    __builtin_amdgcn_s_setprio(0);
    __builtin_amdgcn_sched_barrier(0);
    BARRIER();
  }

  const int r0 = lq * 4;
#pragma unroll
  for (int mi = 0; mi < 8; ++mi)
#pragma unroll
    for (int ni = 0; ni < 4; ++ni)
#pragma unroll
      for (int r = 0; r < 4; ++r) {
        const int gm = m0 + wm * 128 + mi * 16 + r0 + r;
        const int gn = n0 + wn * 64 + ni * 16 + fr;
        const float v = acc[mi][ni][r];
        if (EPI == 0) {
          float vv = v;
          if (bias) vv += bias[gn];
          outb[(size_t)gm * ldo + gn] = f2bf(vv);
        } else if (EPI == 2) {
          const float g = bf2f(gate[(size_t)gm * ldo + gn]);
          const float s = g / (1.f + __expf(-g));
          outb[(size_t)gm * ldo + gn] = f2bf(s * v);
        } else {
          outf[(size_t)bz * zstride + (size_t)gm * ldo + gn] = v;
        }
      }
#undef STAGE
#undef LDA
#undef LDB
}

// ---------------------------------------------------------------------------
// QK^T GEMM: per plane z=(b,h): S[q][kt] = (Q . K^T) * scale, f16 out.
// 256x256 tiles, causal tile-skip (bx>by). lda=2048 (Q), ldw=512 (K).
// ---------------------------------------------------------------------------
__global__ __launch_bounds__(512, 2) void gemm_qk(
    const unsigned short* __restrict__ q, const unsigned short* __restrict__ k,
    unsigned short* __restrict__ s) {
  __shared__ unsigned short lds[65536];
  const int tid = threadIdx.x, lane = tid & 63, wave = tid >> 6;
  const int fr = lane & 15, lq = lane >> 4;
  const int wm = wave >> 2, wn = wave & 3;

  int bx = blockIdx.x, by = blockIdx.y;
  {
    const int nbx = gridDim.x, nwg = nbx * gridDim.y;
    const int lin = by * nbx + bx, cpx = nwg >> 3;
    const int swz = (lin & 7) * cpx + (lin >> 3);
    bx = swz % nbx; by = swz / nbx;
  }
  if (bx > by) return;   // causal: tile entirely above diagonal, never read
  const int z = blockIdx.z, b = z >> 4, h = z & 15, kvh = h >> 2;
  const unsigned short* A = q + (size_t)b * 1024 * HIDDIM + h * HDIM;
  const unsigned short* W = k + (size_t)b * 1024 * KVDIM + kvh * HDIM;
  unsigned short* outp = s + (size_t)z * 1048576;
  const int m0 = by * 256, n0 = bx * 256;

  const int u0 = tid, u1 = tid + 512;
  const int r0s = u0 >> 3, r1s = u1 >> 3;
  const int c0 = ((u0 & 7) ^ (r0s & 7)) << 3, c1 = ((u1 & 7) ^ (r1s & 7)) << 3;
  const size_t offA0 = (size_t)r0s * HIDDIM + c0;
  const size_t offA1 = (size_t)r1s * HIDDIM + c1;
  const size_t offW0 = (size_t)r0s * KVDIM + c0;
  const size_t offW1 = (size_t)r1s * KVDIM + c1;
  const unsigned short* gb0 = A + (size_t)m0 * HIDDIM;
  const unsigned short* gb1 = A + (size_t)(m0 + 128) * HIDDIM;
  const unsigned short* gb2 = W + (size_t)n0 * KVDIM;
  const unsigned short* gb3 = W + (size_t)(n0 + 128) * KVDIM;

#define QSTAGE(h_, tt_, b_)                                                   \
  do {                                                                        \
    const unsigned short* _g =                                                \
        ((h_) == 0 ? gb0 : (h_) == 1 ? gb1 : (h_) == 2 ? gb2 : gb3) +         \
        (size_t)(tt_)*64;                                                     \
    const size_t _o0 = (h_) < 2 ? offA0 : offW0;                              \
    const size_t _o1 = (h_) < 2 ? offA1 : offW1;                              \
    unsigned short* _l = &lds[(b_)*32768 + (h_)*8192 + wave * 512];           \
    gload_lds16(_g + _o0, _l);                                                \
    gload_lds16(_g + _o1, _l + 4096);                                         \
  } while (0)

  const int e0 = lq ^ (fr & 15 & 7);
  const int cbA = wm * 8192;
  const int cbB = (2 + (wn >> 1)) * 8192;
  const int rB0 = (wn & 1) * 64 + fr;

#define QLDA(mi_, ks_, c_)                                                    \
  (*reinterpret_cast<const bf16x8*>(                                          \
      &lds[(c_)*32768 + cbA + ((mi_)*16 + fr) * 64 + ((e0 ^ ((ks_)*4)) << 3)]))
#define QLDB(ni_, ks_, c_)                                                    \
  (*reinterpret_cast<const bf16x8*>(                                          \
      &lds[(c_)*32768 + cbB + (rB0 + (ni_)*16) * 64 + ((e0 ^ ((ks_)*4)) << 3)]))

  f32x4 acc[8][4] = {};
  bf16x8 aF[4], bF[4];

  QSTAGE(0, 0, 0); QSTAGE(1, 0, 0); QSTAGE(2, 0, 0); QSTAGE(3, 0, 0);

  for (int t = 0; t < 2; ++t) {
    const int c = t & 1;
    if (t == 0) {
      QSTAGE(0, 1, 1); QSTAGE(2, 1, 1);
      asm volatile("s_waitcnt vmcnt(4)" ::: "memory");
    } else {
      asm volatile("s_waitcnt vmcnt(0)" ::: "memory");
    }
    BARRIER();
    bF[0] = QLDB(0, 0, c); bF[1] = QLDB(1, 0, c);
    bF[2] = QLDB(2, 0, c); bF[3] = QLDB(3, 0, c);
    aF[0] = QLDA(0, 0, c); aF[1] = QLDA(1, 0, c);
    aF[2] = QLDA(2, 0, c); aF[3] = QLDA(3, 0, c);
    if (t == 0) { QSTAGE(1, 1, 1); QSTAGE(3, 1, 1); }
    BARRIER();
    __builtin_amdgcn_s_setprio(1);
    mfma16<0>(aF, bF, acc);
    __builtin_amdgcn_s_setprio(0);
    __builtin_amdgcn_sched_barrier(0);
    BARRIER();
    aF[0] = QLDA(4, 0, c); aF[1] = QLDA(5, 0, c);
    aF[2] = QLDA(6, 0, c); aF[3] = QLDA(7, 0, c);
    BARRIER();
    __builtin_amdgcn_s_setprio(1);
    mfma16<4>(aF, bF, acc);
    __builtin_amdgcn_s_setprio(0);
    __builtin_amdgcn_sched_barrier(0);
    BARRIER();
    bF[0] = QLDB(0, 1, c); bF[1] = QLDB(1, 1, c);
    bF[2] = QLDB(2, 1, c); bF[3] = QLDB(3, 1, c);
    aF[0] = QLDA(0, 1, c); aF[1] = QLDA(1, 1, c);
    aF[2] = QLDA(2, 1, c); aF[3] = QLDA(3, 1, c);
    BARRIER();
    __builtin_amdgcn_s_setprio(1);
    mfma16<0>(aF, bF, acc);
    __builtin_amdgcn_s_setprio(0);
    __builtin_amdgcn_sched_barrier(0);
    BARRIER();
    aF[0] = QLDA(4, 1, c); aF[1] = QLDA(5, 1, c);
    aF[2] = QLDA(6, 1, c); aF[3] = QLDA(7, 1, c);
    BARRIER();
    __builtin_amdgcn_s_setprio(1);
    mfma16<4>(aF, bF, acc);
    __builtin_amdgcn_s_setprio(0);
    __builtin_amdgcn_sched_barrier(0);
    BARRIER();
  }

  const float scale = 0.08838834764831845f;   // 1/sqrt(128)
  const int r0 = lq * 4;
#pragma unroll
  for (int mi = 0; mi < 8; ++mi)
#pragma unroll
    for (int ni = 0; ni < 4; ++ni)
#pragma unroll
      for (int r = 0; r < 4; ++r) {
        const int gm = m0 + wm * 128 + mi * 16 + r0 + r;
        const int gn = n0 + wn * 64 + ni * 16 + fr;
        outp[(size_t)gm * 1024 + gn] = f2h(acc[mi][ni][r] * scale);
      }
#undef QSTAGE
#undef QLDA
#undef QLDB
}

// ---------------------------------------------------------------------------
// Row softmax, in place: row = (z*1024 + q). Reads f16 S cols 0..q, writes
// bf16 P (cols > q zeroed). One 256-thread block per row, 4 cols/thread.
// ---------------------------------------------------------------------------
__global__ __launch_bounds__(256) void softmax_rows(unsigned short* __restrict__ s) {
  const int row = blockIdx.x, tid = threadIdx.x;
  const int lane = tid & 63, wave = tid >> 6;
  const int qv = row & 1023;
  unsigned short* r = s + (size_t)row * 1024;
  const int col = tid * 4;
  u16x4 raw = *reinterpret_cast<const u16x4*>(r + col);
  float v[4];
#pragma unroll
  for (int j = 0; j < 4; ++j)
    v[j] = (col + j <= qv) ? h2f(((unsigned short*)&raw)[j]) : -1e30f;
  float mx = fmaxf(fmaxf(v[0], v[1]), fmaxf(v[2], v[3]));
#pragma unroll
  for (int off = 1; off < 64; off <<= 1) mx = fmaxf(mx, __shfl_xor(mx, off, 64));
  __shared__ float redm[4], reds[4];
  if (lane == 0) redm[wave] = mx;
  __syncthreads();
  const float M = fmaxf(fmaxf(redm[0], redm[1]), fmaxf(redm[2], redm[3]));
  float e[4], ts = 0.f;
#pragma unroll
  for (int j = 0; j < 4; ++j) {
    e[j] = (col + j <= qv) ? __expf(v[j] - M) : 0.f;
    ts += e[j];
  }
#pragma unroll
  for (int off = 1; off < 64; off <<= 1) ts += __shfl_xor(ts, off, 64);
  if (lane == 0) reds[wave] = ts;
  __syncthreads();
  const float inv = 1.f / (reds[0] + reds[1] + reds[2] + reds[3]);
  u16x4 o;
  o.x = f2bf(e[0] * inv); o.y = f2bf(e[1] * inv);
  o.z = f2bf(e[2] * inv); o.w = f2bf(e[3] * inv);
  *reinterpret_cast<u16x4*>(r + col) = o;
}

// ---------------------------------------------------------------------------
// PV GEMM: per plane z=(b,h): O[q][d] = P[q][kv] * V^T[d][kv]^T.
// BM=256, BN=64, BK=64, 4 waves (wave owns 64 q-rows). Causal: K-tiles per
// block = by*4+4. A = P (bf16, lda=1024), W = vt rows d (ldw=1024).
// Out: ao[(b*1024+q)*2048 + h*128 + d] bf16. Grid (2, 4, 32).
// ---------------------------------------------------------------------------
__global__ __launch_bounds__(256, 2) void gemm_pv(
    const unsigned short* __restrict__ p, const unsigned short* __restrict__ vt,
    unsigned short* __restrict__ ao) {
  __shared__ unsigned short lds[40960];   // 2 bufs x (A 16384 + B 4096) elems
  const int tid = threadIdx.x, lane = tid & 63, wave = tid >> 6;
  const int fr = lane & 15, lq = lane >> 4;
  const int bxn = blockIdx.x, by = blockIdx.y, z = blockIdx.z;
  const int b = z >> 4, h = z & 15, kvh = h >> 2;
  const int m0p = by * 256, n0 = bxn * 64;
  const int NT = by * 4 + 4;

  const unsigned short* A = p + (size_t)z * 1048576 + (size_t)m0p * 1024;
  const unsigned short* W =
      vt + ((size_t)(b * 4 + kvh) * 128 + n0) * 1024;

  // staging source offsets
  // A: units u = wave*512 + j*64 + lane, j=0..7 ; row=u>>3 (0..255)
  // B: units u = wave*128 + j*64 + lane, j=0..1 ; row=u>>3 (0..63)
#define PVSTAGE(tt_, c_)                                                      \
  do {                                                                        \
    _Pragma("unroll")                                                         \
    for (int j = 0; j < 8; ++j) {                                             \
      const int u = wave * 512 + j * 64 + lane;                               \
      const int rw = u >> 3;                                                  \
      gload_lds16(A + (size_t)rw * 1024 + (((u & 7) ^ (rw & 7)) << 3) +       \
                      (size_t)(tt_)*64,                                       \
                  &lds[(c_)*20480 + wave * 4096 + j * 512]);                  \
    }                                                                         \
    _Pragma("unroll")                                                         \
    for (int j = 0; j < 2; ++j) {                                             \
      const int u = wave * 128 + j * 64 + lane;                               \
      const int rw = u >> 3;                                                  \
      gload_lds16(W + (size_t)rw * 1024 + (((u & 7) ^ (rw & 7)) << 3) +       \
                      (size_t)(tt_)*64,                                       \
                  &lds[(c_)*20480 + 16384 + wave * 1024 + j * 512]);          \
    }                                                                         \
  } while (0)

  const int e0 = lq ^ (fr & 7);
#define PVLDA(mi_, ks_, c_)                                                   \
  (*reinterpret_cast<const bf16x8*>(                                          \
      &lds[(c_)*20480 + (wave * 64 + (mi_)*16 + fr) * 64 +                    \
           ((e0 ^ ((ks_)*4)) << 3)]))
#define PVLDB(ni_, ks_, c_)                                                   \
  (*reinterpret_cast<const bf16x8*>(                                          \
      &lds[(c_)*20480 + 16384 + ((ni_)*16 + fr) * 64 +                        \
           ((e0 ^ ((ks_)*4)) << 3)]))

  f32x4 acc[4][4] = {};
  bf16x8 aF[4], bF[4];

  PVSTAGE(0, 0);

  for (int t = 0; t < NT; ++t) {
    const int c = t & 1;
    if (t + 1 < NT) {
      PVSTAGE(t + 1, c ^ 1);
      asm volatile("s_waitcnt vmcnt(10)" ::: "memory");
    } else {
      asm volatile("s_waitcnt vmcnt(0)" ::: "memory");
    }
    BARRIER();
#pragma unroll
    for (int ks = 0; ks < 2; ++ks) {
      bF[0] = PVLDB(0, ks, c); bF[1] = PVLDB(1, ks, c);
      bF[2] = PVLDB(2, ks, c); bF[3] = PVLDB(3, ks, c);
      aF[0] = PVLDA(0, ks, c); aF[1] = PVLDA(1, ks, c);
      aF[2] = PVLDA(2, ks, c); aF[3] = PVLDA(3, ks, c);
      BARRIER();
      __builtin_amdgcn_s_setprio(1);
#pragma unroll
      for (int ni = 0; ni < 4; ++ni)
#pragma unroll
        for (int mi = 0; mi < 4; ++mi)
          acc[mi][ni] = __builtin_amdgcn_mfma_f32_16x16x32_bf16(
              aF[mi], bF[ni], acc[mi][ni], 0, 0, 0);
      __builtin_amdgcn_s_setprio(0);
      __builtin_amdgcn_sched_barrier(0);
      BARRIER();
    }
  }

  const int r0 = lq * 4;
#pragma unroll
  for (int mi = 0; mi < 4; ++mi)
#pragma unroll
    for (int ni = 0; ni < 4; ++ni)
#pragma unroll
      for (int r = 0; r < 4; ++r) {
        const int gm = m0p + wave * 64 + mi * 16 + r0 + r;   // q within plane
        const int gn = n0 + ni * 16 + fr;                    // d within head
        ao[(size_t)(b * 1024 + gm) * HIDDIM + h * HDIM + gn] =
            f2bf(acc[mi][ni][r]);
      }
#undef PVSTAGE
#undef PVLDA
#undef PVLDB
#undef BARRIER
}

// x[i] += sum_{s<ks} p[s*zs4*4 + i]
__global__ __launch_bounds__(256) void reduce_addk(
    float* __restrict__ x, const float* __restrict__ p, int n4, int ks,
    size_t zs4) {
  const f32x4* pv = reinterpret_cast<const f32x4*>(p);
  f32x4* xv = reinterpret_cast<f32x4*>(x);
  for (int i = blockIdx.x * 256 + threadIdx.x; i < n4; i += gridDim.x * 256) {
    f32x4 s = pv[i];
    for (int sp = 1; sp < ks; ++sp) s += pv[(size_t)sp * zs4 + i];
    xv[i] += s;
  }
}

// ---------------------------------------------------------------------------
// QKV split-K2 reduce + bias + RoPE + V-transpose, all fused.
// ---------------------------------------------------------------------------
__global__ __launch_bounds__(256) void reduce_qkv(
    const float* __restrict__ p, const float* __restrict__ qb,
    const float* __restrict__ kb, const float* __restrict__ vb,
    const float* __restrict__ cosb, const float* __restrict__ sinb,
    unsigned short* __restrict__ qo, unsigned short* __restrict__ ko,
    unsigned short* __restrict__ vto) {
  const int i = blockIdx.x * 256 + threadIdx.x;   // < 1,572,864
  const int row = i / 768, c4 = (i - row * 768) * 4;
  const float* p0 = p + (size_t)row * 3072;
  const float* p1 = p + 6291456 + (size_t)row * 3072;
  const f32x4 s = *reinterpret_cast<const f32x4*>(p0 + c4) +
                  *reinterpret_cast<const f32x4*>(p1 + c4);
  if (c4 < 2560) {
    const float* bias; unsigned short* out; int d, ldo;
    if (c4 < 2048) { bias = qb; out = qo; d = c4;        ldo = HIDDIM; }
    else           { bias = kb; out = ko; d = c4 - 2048; ldo = KVDIM; }
    const int dd = d & 127;
    const bool lohalf = (dd < 64);
    const int pc = lohalf ? c4 + 64 : c4 - 64;
    const int pd = lohalf ? d + 64 : d - 64;
    const f32x4 sp = *reinterpret_cast<const f32x4*>(p0 + pc) +
                     *reinterpret_cast<const f32x4*>(p1 + pc);
    const f32x4 bv = *reinterpret_cast<const f32x4*>(bias + d);
    const f32x4 bp = *reinterpret_cast<const f32x4*>(bias + pd);
    const f32x4 cv = *reinterpret_cast<const f32x4*>(cosb + (size_t)row * 128 + dd);
    const f32x4 sv = *reinterpret_cast<const f32x4*>(sinb + (size_t)row * 128 + dd);
    const f32x4 xv = s + bv, pv = sp + bp;
    f32x4 o;
    if (lohalf) o = xv * cv - pv * sv;
    else        o = xv * cv + pv * sv;
    u16x4 ob;
    ob.x = f2bf(o.x); ob.y = f2bf(o.y); ob.z = f2bf(o.z); ob.w = f2bf(o.w);
    *reinterpret_cast<u16x4*>(out + (size_t)row * ldo + d) = ob;
  } else {
    const int d = c4 - 2560;
    const int kvh = d >> 7, dd = d & 127;
    const int b = row >> 10, t = row & 1023;
    const f32x4 bv = *reinterpret_cast<const f32x4*>(vb + d);
    const f32x4 o = s + bv;
    unsigned short* vr =
        vto + ((size_t)(b * 4 + kvh) * 128 + dd) * 1024 + t;
    vr[0] = f2bf(o.x); vr[1024] = f2bf(o.y);
    vr[2048] = f2bf(o.z); vr[3072] = f2bf(o.w);
  }
}

// ---------------------------------------------------------------------------
extern "C" void kernel_launch(void* const* d_in, const int* in_sizes, int n_in,
                              void* d_out, int out_size, void* d_ws,
                              size_t ws_size, hipStream_t stream) {
  (void)in_sizes; (void)n_in; (void)out_size; (void)ws_size;
  const float* hidden = (const float*)d_in[0];
  const float* cosb  = (const float*)d_in[1];
  const float* sinb  = (const float*)d_in[2];
  const float* qw    = (const float*)d_in[3];
  const float* qbias = (const float*)d_in[4];
  const float* kw    = (const float*)d_in[5];
  const float* kbias = (const float*)d_in[6];
  const float* vw    = (const float*)d_in[7];
  const float* vbias = (const float*)d_in[8];
  const float* ow    = (const float*)d_in[9];
  const float* gw    = (const float*)d_in[10];
  const float* uw    = (const float*)d_in[11];
  const float* dw    = (const float*)d_in[12];
  const float* ln1   = (const float*)d_in[13];
  const float* ln2   = (const float*)d_in[14];
  const float* normw = (const float*)d_in[15];

  char* ws = (char*)d_ws;
  float* x               = (float*)ws;                          // 16,777,216 B
  unsigned short* hbuf   = (unsigned short*)(ws + 16777216);    //  8,388,608
  unsigned short* qbuf   = (unsigned short*)(ws + 25165824);    //  8,388,608
  unsigned short* kbuf   = (unsigned short*)(ws + 33554432);    //  2,097,152
  unsigned short* vtbuf  = (unsigned short*)(ws + 35651584);    //  2,097,152
  unsigned short* aobuf  = (unsigned short*)(ws + 39845888);    //  8,388,608
  unsigned short* gatebuf= (unsigned short*)(ws + 48234496);    // 23,068,672
  unsigned short* actbuf = (unsigned short*)(ws + 71303168);    // 23,068,672
  unsigned short* wcvt   = (unsigned short*)(ws + 94371840);    // 23,068,672
  // total: 117,440,512 bytes
  //
  // Scratch overlays (all in regions dead at time-of-use):
  //  - pbufQKV (50.3 MB) at 37748736 (aobuf..actbuf head): dead during QKV.
  float* pbufQKV = (float*)(ws + 37748736);
  //  - sbuf: S/P planes, 32x1024x1024 u16 = 64 MB at gatebuf..wcvt head.
  //    Written by gemm_qk AFTER reduce_qkv consumed pbufQKV; dead before gate.
  unsigned short* sbuf = (unsigned short*)(ws + 48234496);
  //  - pbufO (33.5 MB) at gatebuf (dead during O-proj, sbuf dead by then).
  float* pbufO = (float*)(ws + 48234496);
  //  - pbufD (50.3 MB) at hbuf..gatebuf (dead during down).
  float* pbufD = (float*)(ws + 16777216);

  unsigned short* wq16 = wcvt;                 // [3072][2048] bf16
  unsigned short* wk16 = wcvt + 4194304;
  unsigned short* wv16 = wcvt + 5242880;

  hipMemcpyAsync(x, hidden, (size_t)NTOK * HIDDIM * 4,
                 hipMemcpyDeviceToDevice, stream);

  for (int l = 0; l < 4; ++l) {
    const float* qw_l = qw + (size_t)l * 2048 * 2048;
    const float* qb_l = qbias + (size_t)l * 2048;
    const float* kw_l = kw + (size_t)l * 512 * 2048;
    const float* kb_l = kbias + (size_t)l * 512;
    const float* vw_l = vw + (size_t)l * 512 * 2048;
    const float* vb_l = vbias + (size_t)l * 512;
    const float* ow_l = ow + (size_t)l * 2048 * 2048;
    const float* gw_l = gw + (size_t)l * 5632 * 2048;
    const float* uw_l = uw + (size_t)l * 5632 * 2048;
    const float* dw_l = dw + (size_t)l * 2048 * 5632;

    rmsnorm_kernel<0><<<NTOK, 256, 0, stream>>>(x, ln1 + l * 2048, hbuf);
    cvt_kernel<<<2048, 256, 0, stream>>>(qw_l, wq16, 524288);
    cvt_kernel<<<512, 256, 0, stream>>>(kw_l, wk16, 131072);
    cvt_kernel<<<512, 256, 0, stream>>>(vw_l, wv16, 131072);
    // fused QKV: [2048,2048] x [3072,2048]^T, split-K2 8-phase
    gemm8p<3><<<dim3(12, 8, 2), 512, 0, stream>>>(
        hbuf, wcvt, nullptr, nullptr, nullptr, pbufQKV, 2048, 3072, 16, 32,
        (size_t)6291456);
    reduce_qkv<<<6144, 256, 0, stream>>>(pbufQKV, qb_l, kb_l, vb_l, cosb,
                                         sinb, qbuf, kbuf, vtbuf);

    // attention = QK GEMM -> row softmax -> PV GEMM
    gemm_qk<<<dim3(4, 4, 32), 512, 0, stream>>>(qbuf, kbuf, sbuf);
    softmax_rows<<<32768, 256, 0, stream>>>(sbuf);
    gemm_pv<<<dim3(2, 4, 32), 256, 0, stream>>>(sbuf, vtbuf, aobuf);

    // O-proj: split-K2 8-phase -> fp32 partials -> x += sum
    cvt_kernel<<<2048, 256, 0, stream>>>(ow_l, wcvt, 524288);
    gemm8p<3><<<dim3(8, 8, 2), 512, 0, stream>>>(
        aobuf, wcvt, nullptr, nullptr, nullptr, pbufO, 2048, 2048, 16, 32,
        (size_t)4194304);
    reduce_addk<<<2048, 256, 0, stream>>>(x, pbufO, 1048576, 2,
                                          (size_t)1048576);

    rmsnorm_kernel<0><<<NTOK, 256, 0, stream>>>(x, ln2 + l * 2048, hbuf);

    // gate
    cvt_kernel<<<5632, 256, 0, stream>>>(gw_l, wcvt, 1441792);
    gemm8p<0><<<dim3(22, 8, 1), 512, 0, stream>>>(
        hbuf, wcvt, nullptr, gatebuf, nullptr, nullptr, 2048, 5632, 32, 32,
        (size_t)0);
    // up (+ silu(gate) epilogue)
    cvt_kernel<<<5632, 256, 0, stream>>>(uw_l, wcvt, 1441792);
    gemm8p<2><<<dim3(22, 8, 1), 512, 0, stream>>>(
        hbuf, wcvt, nullptr, actbuf, gatebuf, nullptr, 2048, 5632, 32, 32,
        (size_t)0);
    // down: split-K3 -> fp32 partials -> x += sum
    cvt_kernel<<<5632, 256, 0, stream>>>(dw_l, wcvt, 1441792);
    gemm8p<3><<<dim3(8, 8, 3), 512, 0, stream>>>(
        actbuf, wcvt, nullptr, nullptr, nullptr, pbufD, 5632, 2048, 30, 88,
        (size_t)4194304);
    reduce_addk<<<2048, 256, 0, stream>>>(x, pbufD, 1048576, 3,
                                          (size_t)1048576);
  }
  rmsnorm_kernel<1><<<NTOK, 256, 0, stream>>>(x, normw, d_out);
}

// Round 7
// 1694.708 us; speedup vs baseline: 1.2037x; 1.0570x over previous
//
#include <hip/hip_runtime.h>

// ---------------------------------------------------------------------------
// DecoderBackbone: 4-layer llama-style decoder, B=2 T=1024 HID=2048,
// NH=16 NKV=4 HD=128, INTER=5632. fp32 residual stream, bf16 MFMA GEMMs.
// R7: gate+up merged into one interleaved GEMM with in-LDS silu exchange;
// bf16 split-K partials everywhere; reduce+RMSNorm fused; causal-trimmed
// softmax.
// ---------------------------------------------------------------------------

typedef __attribute__((ext_vector_type(8))) __bf16 bf16x8;
typedef __attribute__((ext_vector_type(4))) float f32x4;
typedef __attribute__((ext_vector_type(4))) unsigned short u16x4;

#define DEV __device__ __forceinline__
#define BARRIER() asm volatile("s_barrier" ::: "memory")

#define NTOK 2048     // B*T
#define HIDDIM 2048
#define NHEADS 16
#define NKVH 4
#define HDIM 128
#define KVDIM 512     // NKV*HD
#define INTERDIM 5632

DEV unsigned short f2bf(float f) {
  union { float f; unsigned u; } a; a.f = f;
  unsigned r = a.u + 0x7fffu + ((a.u >> 16) & 1u);   // RNE
  return (unsigned short)(r >> 16);
}
DEV float bf2f(unsigned short h) {
  union { unsigned u; float f; } a; a.u = ((unsigned)h) << 16;
  return a.f;
}
DEV unsigned short f2h(float f) {
  union { _Float16 h; unsigned short u; } c; c.h = (_Float16)f; return c.u;
}
DEV float h2f(unsigned short u) {
  union { unsigned short u; _Float16 h; } c; c.u = u; return (float)c.h;
}
DEV void gload_lds16(const void* g, void* l) {
  __builtin_amdgcn_global_load_lds(
      (const __attribute__((address_space(1))) unsigned int*)(g),
      (__attribute__((address_space(3))) unsigned int*)(l), 16, 0, 0);
}

// ---------------------------------------------------------------------------
// fp32 -> bf16 weight convert, 8 elems/thread. n8 = n/8.
// ---------------------------------------------------------------------------
__global__ __launch_bounds__(256) void cvt_kernel(
    const float* __restrict__ in, unsigned short* __restrict__ out, int n8) {
  const int i = blockIdx.x * 256 + threadIdx.x;
  if (i >= n8) return;
  const f32x4* p = reinterpret_cast<const f32x4*>(in) + (size_t)i * 2;
  const f32x4 a = p[0], b = p[1];
  bf16x8 o;
  o[0] = (__bf16)a.x; o[1] = (__bf16)a.y; o[2] = (__bf16)a.z; o[3] = (__bf16)a.w;
  o[4] = (__bf16)b.x; o[5] = (__bf16)b.y; o[6] = (__bf16)b.z; o[7] = (__bf16)b.w;
  *reinterpret_cast<bf16x8*>(out + (size_t)i * 8) = o;
}

// Interleaved gate/up convert: out[11264][2048], rows t*256..t*256+127 = gate
// rows t*128.., rows t*256+128.. = up rows t*128.. (t = 0..43).
__global__ __launch_bounds__(256) void cvt_gu(
    const float* __restrict__ gw, const float* __restrict__ uw,
    unsigned short* __restrict__ out) {
  const int i = blockIdx.x * 256 + threadIdx.x;   // 8-elem group, < 11264*256
  const int row = i >> 8, g8 = i & 255;
  const int t = row >> 8, sub = row & 255;
  const float* src = (sub < 128)
                         ? gw + (size_t)(t * 128 + sub) * 2048
                         : uw + (size_t)(t * 128 + sub - 128) * 2048;
  const f32x4* p = reinterpret_cast<const f32x4*>(src) + (size_t)g8 * 2;
  const f32x4 a = p[0], b = p[1];
  bf16x8 o;
  o[0] = (__bf16)a.x; o[1] = (__bf16)a.y; o[2] = (__bf16)a.z; o[3] = (__bf16)a.w;
  o[4] = (__bf16)b.x; o[5] = (__bf16)b.y; o[6] = (__bf16)b.z; o[7] = (__bf16)b.w;
  *reinterpret_cast<bf16x8*>(out + (size_t)row * 2048 + g8 * 8) = o;
}

// ---------------------------------------------------------------------------
// RMSNorm: x fp32 [row][2048] -> out bf16 (layer-0 ln1 only).
// ---------------------------------------------------------------------------
template <int OUTF32>
__global__ __launch_bounds__(256) void rmsnorm_kernel(
    const float* __restrict__ x, const float* __restrict__ w,
    void* __restrict__ outp) {
  const int row = blockIdx.x, tid = threadIdx.x;
  const int lane = tid & 63, wave = tid >> 6;
  const float* xr = x + (size_t)row * HIDDIM;
  f32x4 v0 = *reinterpret_cast<const f32x4*>(xr + tid * 4);
  f32x4 v1 = *reinterpret_cast<const f32x4*>(xr + 1024 + tid * 4);
  float ss = v0.x * v0.x + v0.y * v0.y + v0.z * v0.z + v0.w * v0.w +
             v1.x * v1.x + v1.y * v1.y + v1.z * v1.z + v1.w * v1.w;
#pragma unroll
  for (int off = 1; off < 64; off <<= 1) ss += __shfl_xor(ss, off, 64);
  __shared__ float red[4];
  if (lane == 0) red[wave] = ss;
  __syncthreads();
  ss = red[0] + red[1] + red[2] + red[3];
  const float rs = rsqrtf(ss * (1.0f / 2048.0f) + 1e-6f);
  f32x4 w0 = *reinterpret_cast<const f32x4*>(w + tid * 4);
  f32x4 w1 = *reinterpret_cast<const f32x4*>(w + 1024 + tid * 4);
  if (OUTF32) {
    float* o = (float*)outp + (size_t)row * HIDDIM;
    f32x4 o0, o1;
    o0.x = v0.x * rs * w0.x; o0.y = v0.y * rs * w0.y;
    o0.z = v0.z * rs * w0.z; o0.w = v0.w * rs * w0.w;
    o1.x = v1.x * rs * w1.x; o1.y = v1.y * rs * w1.y;
    o1.z = v1.z * rs * w1.z; o1.w = v1.w * rs * w1.w;
    *reinterpret_cast<f32x4*>(o + tid * 4) = o0;
    *reinterpret_cast<f32x4*>(o + 1024 + tid * 4) = o1;
  } else {
    unsigned short* o = (unsigned short*)outp + (size_t)row * HIDDIM;
    u16x4 p0, p1;
    p0.x = f2bf(v0.x * rs * w0.x); p0.y = f2bf(v0.y * rs * w0.y);
    p0.z = f2bf(v0.z * rs * w0.z); p0.w = f2bf(v0.w * rs * w0.w);
    p1.x = f2bf(v1.x * rs * w1.x); p1.y = f2bf(v1.y * rs * w1.y);
    p1.z = f2bf(v1.z * rs * w1.z); p1.w = f2bf(v1.w * rs * w1.w);
    *reinterpret_cast<u16x4*>(o + tid * 4) = p0;
    *reinterpret_cast<u16x4*>(o + 1024 + tid * 4) = p1;
  }
}

// ---------------------------------------------------------------------------
// Fused split-K reduce + residual add + RMSNorm. One block per row:
// x[row] += sum_s p[s]; write x back; h = rmsnorm(x)*w -> outp (bf16/f32).
// ---------------------------------------------------------------------------
template <int KS, int OUTF32>
__global__ __launch_bounds__(256) void reduce_rms(
    float* __restrict__ x, const unsigned short* __restrict__ p, size_t zs,
    const float* __restrict__ w, void* __restrict__ outp) {
  const int row = blockIdx.x, tid = threadIdx.x;
  const int lane = tid & 63, wave = tid >> 6;
  float* xr = x + (size_t)row * HIDDIM;
  f32x4 v0 = *reinterpret_cast<const f32x4*>(xr + tid * 4);
  f32x4 v1 = *reinterpret_cast<const f32x4*>(xr + 1024 + tid * 4);
#pragma unroll
  for (int s = 0; s < KS; ++s) {
    const unsigned short* pr = p + (size_t)s * zs + (size_t)row * HIDDIM;
    u16x4 a = *reinterpret_cast<const u16x4*>(pr + tid * 4);
    u16x4 b = *reinterpret_cast<const u16x4*>(pr + 1024 + tid * 4);
    v0.x += bf2f(a.x); v0.y += bf2f(a.y); v0.z += bf2f(a.z); v0.w += bf2f(a.w);
    v1.x += bf2f(b.x); v1.y += bf2f(b.y); v1.z += bf2f(b.z); v1.w += bf2f(b.w);
  }
  *reinterpret_cast<f32x4*>(xr + tid * 4) = v0;
  *reinterpret_cast<f32x4*>(xr + 1024 + tid * 4) = v1;
  float ss = v0.x * v0.x + v0.y * v0.y + v0.z * v0.z + v0.w * v0.w +
             v1.x * v1.x + v1.y * v1.y + v1.z * v1.z + v1.w * v1.w;
#pragma unroll
  for (int off = 1; off < 64; off <<= 1) ss += __shfl_xor(ss, off, 64);
  __shared__ float red[4];
  if (lane == 0) red[wave] = ss;
  __syncthreads();
  ss = red[0] + red[1] + red[2] + red[3];
  const float rs = rsqrtf(ss * (1.0f / 2048.0f) + 1e-6f);
  f32x4 w0 = *reinterpret_cast<const f32x4*>(w + tid * 4);
  f32x4 w1 = *reinterpret_cast<const f32x4*>(w + 1024 + tid * 4);
  if (OUTF32) {
    float* o = (float*)outp + (size_t)row * HIDDIM;
    f32x4 o0, o1;
    o0.x = v0.x * rs * w0.x; o0.y = v0.y * rs * w0.y;
    o0.z = v0.z * rs * w0.z; o0.w = v0.w * rs * w0.w;
    o1.x = v1.x * rs * w1.x; o1.y = v1.y * rs * w1.y;
    o1.z = v1.z * rs * w1.z; o1.w = v1.w * rs * w1.w;
    *reinterpret_cast<f32x4*>(o + tid * 4) = o0;
    *reinterpret_cast<f32x4*>(o + 1024 + tid * 4) = o1;
  } else {
    unsigned short* o = (unsigned short*)outp + (size_t)row * HIDDIM;
    u16x4 p0, p1;
    p0.x = f2bf(v0.x * rs * w0.x); p0.y = f2bf(v0.y * rs * w0.y);
    p0.z = f2bf(v0.z * rs * w0.z); p0.w = f2bf(v0.w * rs * w0.w);
    p1.x = f2bf(v1.x * rs * w1.x); p1.y = f2bf(v1.y * rs * w1.y);
    p1.z = f2bf(v1.z * rs * w1.z); p1.w = f2bf(v1.w * rs * w1.w);
    *reinterpret_cast<u16x4*>(o + tid * 4) = p0;
    *reinterpret_cast<u16x4*>(o + 1024 + tid * 4) = p1;
  }
}

// ---------------------------------------------------------------------------
// 256x256 8-phase GEMM (T2+T3+T4+T5). C = A[M,K] * W[N,K]^T, bf16 in.
// Writes bf16 partial plane: outp[bz*zstride + gm*ldo + gn].
// ---------------------------------------------------------------------------
template <int MB>
DEV void mfma16(const bf16x8 (&aF)[4], const bf16x8 (&bF)[4],
                f32x4 (&acc)[8][4]) {
#pragma unroll
  for (int ni = 0; ni < 4; ++ni)
#pragma unroll
    for (int mi = 0; mi < 4; ++mi)
      acc[MB + mi][ni] = __builtin_amdgcn_mfma_f32_16x16x32_bf16(
          aF[mi], bF[ni], acc[MB + mi][ni], 0, 0, 0);
}

__global__ __launch_bounds__(512, 2) void gemm8p(
    const unsigned short* __restrict__ A, const unsigned short* __restrict__ W,
    unsigned short* __restrict__ outp, int K, int ldo, int kt_split,
    int kt_tot, size_t zstride) {
  __shared__ unsigned short lds[65536];   // 128 KiB: [buf2][half4][128*64]
  const int tid = threadIdx.x, lane = tid & 63, wave = tid >> 6;
  const int fr = lane & 15, lq = lane >> 4;
  const int wm = wave >> 2, wn = wave & 3;

  int bx = blockIdx.x, by = blockIdx.y;
  {
    const int nbx = gridDim.x, nwg = nbx * gridDim.y;
    const int lin = by * nbx + bx, cpx = nwg >> 3;
    const int swz = (lin & 7) * cpx + (lin >> 3);
    bx = swz % nbx; by = swz / nbx;
  }
  const int m0 = by * 256, n0 = bx * 256;
  const int bz = blockIdx.z;
  const int t0 = bz * kt_split;
  int NT = kt_tot - t0; if (NT > kt_split) NT = kt_split;

  const int u0 = tid, u1 = tid + 512;
  const int r0s = u0 >> 3, r1s = u1 >> 3;
  const size_t off0 = (size_t)r0s * K + (size_t)((((u0 & 7) ^ (r0s & 7))) << 3);
  const size_t off1 = (size_t)r1s * K + (size_t)((((u1 & 7) ^ (r1s & 7))) << 3);
  const unsigned short* gb0 = A + (size_t)(m0)*K + (size_t)t0 * 64;
  const unsigned short* gb1 = A + (size_t)(m0 + 128) * K + (size_t)t0 * 64;
  const unsigned short* gb2 = W + (size_t)(n0)*K + (size_t)t0 * 64;
  const unsigned short* gb3 = W + (size_t)(n0 + 128) * K + (size_t)t0 * 64;

#define STAGE(h_, tt_, b_)                                                    \
  do {                                                                        \
    const unsigned short* _g =                                                \
        ((h_) == 0 ? gb0 : (h_) == 1 ? gb1 : (h_) == 2 ? gb2 : gb3) +         \
        (size_t)(tt_)*64;                                                     \
    unsigned short* _l = &lds[(b_)*32768 + (h_)*8192 + wave * 512];           \
    gload_lds16(_g + off0, _l);                                               \
    gload_lds16(_g + off1, _l + 4096);                                        \
  } while (0)

  const int e0 = lq ^ (fr & 7);
  const int cbA = wm * 8192;
  const int cbB = (2 + (wn >> 1)) * 8192;
  const int rB0 = (wn & 1) * 64 + fr;

#define LDA(mi_, ks_, c_)                                                     \
  (*reinterpret_cast<const bf16x8*>(                                          \
      &lds[(c_)*32768 + cbA + ((mi_)*16 + fr) * 64 + ((e0 ^ ((ks_)*4)) << 3)]))
#define LDB(ni_, ks_, c_)                                                     \
  (*reinterpret_cast<const bf16x8*>(                                          \
      &lds[(c_)*32768 + cbB + (rB0 + (ni_)*16) * 64 + ((e0 ^ ((ks_)*4)) << 3)]))

  f32x4 acc[8][4] = {};
  bf16x8 aF[4], bF[4];

  STAGE(0, 0, 0); STAGE(1, 0, 0); STAGE(2, 0, 0); STAGE(3, 0, 0);

  for (int t = 0; t < NT; ++t) {
    const int c = t & 1;
    if (t + 1 < NT) {
      STAGE(0, t + 1, c ^ 1);
      STAGE(2, t + 1, c ^ 1);
      asm volatile("s_waitcnt vmcnt(4)" ::: "memory");
    } else {
      asm volatile("s_waitcnt vmcnt(0)" ::: "memory");
    }
    BARRIER();

    bF[0] = LDB(0, 0, c); bF[1] = LDB(1, 0, c);
    bF[2] = LDB(2, 0, c); bF[3] = LDB(3, 0, c);
    aF[0] = LDA(0, 0, c); aF[1] = LDA(1, 0, c);
    aF[2] = LDA(2, 0, c); aF[3] = LDA(3, 0, c);
    if (t + 1 < NT) { STAGE(1, t + 1, c ^ 1); STAGE(3, t + 1, c ^ 1); }
    BARRIER();
    __builtin_amdgcn_s_setprio(1);
    mfma16<0>(aF, bF, acc);
    __builtin_amdgcn_s_setprio(0);
    __builtin_amdgcn_sched_barrier(0);
    BARRIER();

    aF[0] = LDA(4, 0, c); aF[1] = LDA(5, 0, c);
    aF[2] = LDA(6, 0, c); aF[3] = LDA(7, 0, c);
    BARRIER();
    __builtin_amdgcn_s_setprio(1);
    mfma16<4>(aF, bF, acc);
    __builtin_amdgcn_s_setprio(0);
    __builtin_amdgcn_sched_barrier(0);
    BARRIER();

    bF[0] = LDB(0, 1, c); bF[1] = LDB(1, 1, c);
    bF[2] = LDB(2, 1, c); bF[3] = LDB(3, 1, c);
    aF[0] = LDA(0, 1, c); aF[1] = LDA(1, 1, c);
    aF[2] = LDA(2, 1, c); aF[3] = LDA(3, 1, c);
    BARRIER();
    __builtin_amdgcn_s_setprio(1);
    mfma16<0>(aF, bF, acc);
    __builtin_amdgcn_s_setprio(0);
    __builtin_amdgcn_sched_barrier(0);
    BARRIER();

    aF[0] = LDA(4, 1, c); aF[1] = LDA(5, 1, c);
    aF[2] = LDA(6, 1, c); aF[3] = LDA(7, 1, c);
    BARRIER();
    __builtin_amdgcn_s_setprio(1);
    mfma16<4>(aF, bF, acc);
    __builtin_amdgcn_s_setprio(0);
    __builtin_amdgcn_sched_barrier(0);
    BARRIER();
  }

  const int r0 = lq * 4;
#pragma unroll
  for (int mi = 0; mi < 8; ++mi)
#pragma unroll
    for (int ni = 0; ni < 4; ++ni)
#pragma unroll
      for (int r = 0; r < 4; ++r) {
        const int gm = m0 + wm * 128 + mi * 16 + r0 + r;
        const int gn = n0 + wn * 64 + ni * 16 + fr;
        outp[(size_t)bz * zstride + (size_t)gm * ldo + gn] =
            f2bf(acc[mi][ni][r]);
      }
#undef STAGE
#undef LDA
#undef LDB
}

// ---------------------------------------------------------------------------
// gate+up merged GEMM: W = wgu[11264][2048] (128-row interleave), N-tile 256
// covers 128 gate cols + 128 up cols of the same inter range. Epilogue: gate
// waves (wn<2) publish raw g via LDS (f32), up waves compute silu(g)*v and
// store bf16 to act[2048][5632]. No gatebuf round-trip.
// ---------------------------------------------------------------------------
__global__ __launch_bounds__(512, 2) void gemm_gu(
    const unsigned short* __restrict__ A, const unsigned short* __restrict__ W,
    unsigned short* __restrict__ act) {
  __shared__ unsigned short lds[65536];
  const int tid = threadIdx.x, lane = tid & 63, wave = tid >> 6;
  const int fr = lane & 15, lq = lane >> 4;
  const int wm = wave >> 2, wn = wave & 3;
  const int K = 2048;

  int bx = blockIdx.x, by = blockIdx.y;
  {
    const int nbx = gridDim.x, nwg = nbx * gridDim.y;
    const int lin = by * nbx + bx, cpx = nwg >> 3;
    const int swz = (lin & 7) * cpx + (lin >> 3);
    bx = swz % nbx; by = swz / nbx;
  }
  const int m0 = by * 256, n0 = bx * 256;

  const int u0 = tid, u1 = tid + 512;
  const int r0s = u0 >> 3, r1s = u1 >> 3;
  const size_t off0 = (size_t)r0s * K + (size_t)((((u0 & 7) ^ (r0s & 7))) << 3);
  const size_t off1 = (size_t)r1s * K + (size_t)((((u1 & 7) ^ (r1s & 7))) << 3);
  const unsigned short* gb0 = A + (size_t)(m0)*K;
  const unsigned short* gb1 = A + (size_t)(m0 + 128) * K;
  const unsigned short* gb2 = W + (size_t)(n0)*K;
  const unsigned short* gb3 = W + (size_t)(n0 + 128) * K;

#define STAGE(h_, tt_, b_)                                                    \
  do {                                                                        \
    const unsigned short* _g =                                                \
        ((h_) == 0 ? gb0 : (h_) == 1 ? gb1 : (h_) == 2 ? gb2 : gb3) +         \
        (size_t)(tt_)*64;                                                     \
    unsigned short* _l = &lds[(b_)*32768 + (h_)*8192 + wave * 512];           \
    gload_lds16(_g + off0, _l);                                               \
    gload_lds16(_g + off1, _l + 4096);                                        \
  } while (0)

  const int e0 = lq ^ (fr & 7);
  const int cbA = wm * 8192;
  const int cbB = (2 + (wn >> 1)) * 8192;
  const int rB0 = (wn & 1) * 64 + fr;

#define LDA(mi_, ks_, c_)                                                     \
  (*reinterpret_cast<const bf16x8*>(                                          \
      &lds[(c_)*32768 + cbA + ((mi_)*16 + fr) * 64 + ((e0 ^ ((ks_)*4)) << 3)]))
#define LDB(ni_, ks_, c_)                                                     \
  (*reinterpret_cast<const bf16x8*>(                                          \
      &lds[(c_)*32768 + cbB + (rB0 + (ni_)*16) * 64 + ((e0 ^ ((ks_)*4)) << 3)]))

  f32x4 acc[8][4] = {};
  bf16x8 aF[4], bF[4];

  STAGE(0, 0, 0); STAGE(1, 0, 0); STAGE(2, 0, 0); STAGE(3, 0, 0);

  for (int t = 0; t < 32; ++t) {
    const int c = t & 1;
    if (t + 1 < 32) {
      STAGE(0, t + 1, c ^ 1);
      STAGE(2, t + 1, c ^ 1);
      asm volatile("s_waitcnt vmcnt(4)" ::: "memory");
    } else {
      asm volatile("s_waitcnt vmcnt(0)" ::: "memory");
    }
    BARRIER();
    bF[0] = LDB(0, 0, c); bF[1] = LDB(1, 0, c);
    bF[2] = LDB(2, 0, c); bF[3] = LDB(3, 0, c);
    aF[0] = LDA(0, 0, c); aF[1] = LDA(1, 0, c);
    aF[2] = LDA(2, 0, c); aF[3] = LDA(3, 0, c);
    if (t + 1 < 32) { STAGE(1, t + 1, c ^ 1); STAGE(3, t + 1, c ^ 1); }
    BARRIER();
    __builtin_amdgcn_s_setprio(1);
    mfma16<0>(aF, bF, acc);
    __builtin_amdgcn_s_setprio(0);
    __builtin_amdgcn_sched_barrier(0);
    BARRIER();
    aF[0] = LDA(4, 0, c); aF[1] = LDA(5, 0, c);
    aF[2] = LDA(6, 0, c); aF[3] = LDA(7, 0, c);
    BARRIER();
    __builtin_amdgcn_s_setprio(1);
    mfma16<4>(aF, bF, acc);
    __builtin_amdgcn_s_setprio(0);
    __builtin_amdgcn_sched_barrier(0);
    BARRIER();
    bF[0] = LDB(0, 1, c); bF[1] = LDB(1, 1, c);
    bF[2] = LDB(2, 1, c); bF[3] = LDB(3, 1, c);
    aF[0] = LDA(0, 1, c); aF[1] = LDA(1, 1, c);
    aF[2] = LDA(2, 1, c); aF[3] = LDA(3, 1, c);
    BARRIER();
    __builtin_amdgcn_s_setprio(1);
    mfma16<0>(aF, bF, acc);
    __builtin_amdgcn_s_setprio(0);
    __builtin_amdgcn_sched_barrier(0);
    BARRIER();
    aF[0] = LDA(4, 1, c); aF[1] = LDA(5, 1, c);
    aF[2] = LDA(6, 1, c); aF[3] = LDA(7, 1, c);
    BARRIER();
    __builtin_amdgcn_s_setprio(1);
    mfma16<4>(aF, bF, acc);
    __builtin_amdgcn_s_setprio(0);
    __builtin_amdgcn_sched_barrier(0);
    BARRIER();
  }

  // epilogue: exchange gate values through LDS (f32 view, 32768 floats)
  float* fl = reinterpret_cast<float*>(lds);
  const int r0 = lq * 4;
  __syncthreads();   // all waves past their last lds read
  if (wn < 2) {
#pragma unroll
    for (int mi = 0; mi < 8; ++mi)
#pragma unroll
      for (int ni = 0; ni < 4; ++ni)
#pragma unroll
        for (int r = 0; r < 4; ++r)
          fl[wm * 16384 + (mi * 16 + r0 + r) * 128 + wn * 64 + ni * 16 + fr] =
              acc[mi][ni][r];
  }
  __syncthreads();
  if (wn >= 2) {
    const int wnu = wn - 2;
#pragma unroll
    for (int mi = 0; mi < 8; ++mi)
#pragma unroll
      for (int ni = 0; ni < 4; ++ni)
#pragma unroll
        for (int r = 0; r < 4; ++r) {
          const int mrow = mi * 16 + r0 + r;
          const float g =
              fl[wm * 16384 + mrow * 128 + wnu * 64 + ni * 16 + fr];
          const float s = g / (1.f + __expf(-g));
          const int gm = m0 + wm * 128 + mrow;
          const int ic = (n0 >> 1) + wnu * 64 + ni * 16 + fr;
          act[(size_t)gm * INTERDIM + ic] = f2bf(s * acc[mi][ni][r]);
        }
  }
#undef STAGE
#undef LDA
#undef LDB
}

// ---------------------------------------------------------------------------
// QK^T GEMM: per plane z=(b,h): S[q][kt] = (Q . K^T) * scale, f16 out.
// 256x256 tiles, causal tile-skip (bx>by). lda=2048 (Q), ldw=512 (K).
// ---------------------------------------------------------------------------
__global__ __launch_bounds__(512, 2) void gemm_qk(
    const unsigned short* __restrict__ q, const unsigned short* __restrict__ k,
    unsigned short* __restrict__ s) {
  __shared__ unsigned short lds[65536];
  const int tid = threadIdx.x, lane = tid & 63, wave = tid >> 6;
  const int fr = lane & 15, lq = lane >> 4;
  const int wm = wave >> 2, wn = wave & 3;

  int bx = blockIdx.x, by = blockIdx.y;
  {
    const int nbx = gridDim.x, nwg = nbx * gridDim.y;
    const int lin = by * nbx + bx, cpx = nwg >> 3;
    const int swz = (lin & 7) * cpx + (lin >> 3);
    bx = swz % nbx; by = swz / nbx;
  }
  if (bx > by) return;   // causal: tile never read
  const int z = blockIdx.z, b = z >> 4, h = z & 15, kvh = h >> 2;
  const unsigned short* A = q + (size_t)b * 1024 * HIDDIM + h * HDIM;
  const unsigned short* W = k + (size_t)b * 1024 * KVDIM + kvh * HDIM;
  unsigned short* outp = s + (size_t)z * 1048576;
  const int m0 = by * 256, n0 = bx * 256;

  const int u0 = tid, u1 = tid + 512;
  const int r0s = u0 >> 3, r1s = u1 >> 3;
  const int c0 = ((u0 & 7) ^ (r0s & 7)) << 3, c1 = ((u1 & 7) ^ (r1s & 7)) << 3;
  const size_t offA0 = (size_t)r0s * HIDDIM + c0;
  const size_t offA1 = (size_t)r1s * HIDDIM + c1;
  const size_t offW0 = (size_t)r0s * KVDIM + c0;
  const size_t offW1 = (size_t)r1s * KVDIM + c1;
  const unsigned short* gb0 = A + (size_t)m0 * HIDDIM;
  const unsigned short* gb1 = A + (size_t)(m0 + 128) * HIDDIM;
  const unsigned short* gb2 = W + (size_t)n0 * KVDIM;
  const unsigned short* gb3 = W + (size_t)(n0 + 128) * KVDIM;

#define QSTAGE(h_, tt_, b_)                                                   \
  do {                                                                        \
    const unsigned short* _g =                                                \
        ((h_) == 0 ? gb0 : (h_) == 1 ? gb1 : (h_) == 2 ? gb2 : gb3) +         \
        (size_t)(tt_)*64;                                                     \
    const size_t _o0 = (h_) < 2 ? offA0 : offW0;                              \
    const size_t _o1 = (h_) < 2 ? offA1 : offW1;                              \
    unsigned short* _l = &lds[(b_)*32768 + (h_)*8192 + wave * 512];           \
    gload_lds16(_g + _o0, _l);                                                \
    gload_lds16(_g + _o1, _l + 4096);                                         \
  } while (0)

  const int e0 = lq ^ (fr & 7);
  const int cbA = wm * 8192;
  const int cbB = (2 + (wn >> 1)) * 8192;
  const int rB0 = (wn & 1) * 64 + fr;

#define QLDA(mi_, ks_, c_)                                                    \
  (*reinterpret_cast<const bf16x8*>(                                          \
      &lds[(c_)*32768 + cbA + ((mi_)*16 + fr) * 64 + ((e0 ^ ((ks_)*4)) << 3)]))
#define QLDB(ni_, ks_, c_)                                                    \
  (*reinterpret_cast<const bf16x8*>(                                          \
      &lds[(c_)*32768 + cbB + (rB0 + (ni_)*16) * 64 + ((e0 ^ ((ks_)*4)) << 3)]))

  f32x4 acc[8][4] = {};
  bf16x8 aF[4], bF[4];

  QSTAGE(0, 0, 0); QSTAGE(1, 0, 0); QSTAGE(2, 0, 0); QSTAGE(3, 0, 0);

  for (int t = 0; t < 2; ++t) {
    const int c = t & 1;
    if (t == 0) {
      QSTAGE(0, 1, 1); QSTAGE(2, 1, 1);
      asm volatile("s_waitcnt vmcnt(4)" ::: "memory");
    } else {
      asm volatile("s_waitcnt vmcnt(0)" ::: "memory");
    }
    BARRIER();
    bF[0] = QLDB(0, 0, c); bF[1] = QLDB(1, 0, c);
    bF[2] = QLDB(2, 0, c); bF[3] = QLDB(3, 0, c);
    aF[0] = QLDA(0, 0, c); aF[1] = QLDA(1, 0, c);
    aF[2] = QLDA(2, 0, c); aF[3] = QLDA(3, 0, c);
    if (t == 0) { QSTAGE(1, 1, 1); QSTAGE(3, 1, 1); }
    BARRIER();
    __builtin_amdgcn_s_setprio(1);
    mfma16<0>(aF, bF, acc);
    __builtin_amdgcn_s_setprio(0);
    __builtin_amdgcn_sched_barrier(0);
    BARRIER();
    aF[0] = QLDA(4, 0, c); aF[1] = QLDA(5, 0, c);
    aF[2] = QLDA(6, 0, c); aF[3] = QLDA(7, 0, c);
    BARRIER();
    __builtin_amdgcn_s_setprio(1);
    mfma16<4>(aF, bF, acc);
    __builtin_amdgcn_s_setprio(0);
    __builtin_amdgcn_sched_barrier(0);
    BARRIER();
    bF[0] = QLDB(0, 1, c); bF[1] = QLDB(1, 1, c);
    bF[2] = QLDB(2, 1, c); bF[3] = QLDB(3, 1, c);
    aF[0] = QLDA(0, 1, c); aF[1] = QLDA(1, 1, c);
    aF[2] = QLDA(2, 1, c); aF[3] = QLDA(3, 1, c);
    BARRIER();
    __builtin_amdgcn_s_setprio(1);
    mfma16<0>(aF, bF, acc);
    __builtin_amdgcn_s_setprio(0);
    __builtin_amdgcn_sched_barrier(0);
    BARRIER();
    aF[0] = QLDA(4, 1, c); aF[1] = QLDA(5, 1, c);
    aF[2] = QLDA(6, 1, c); aF[3] = QLDA(7, 1, c);
    BARRIER();
    __builtin_amdgcn_s_setprio(1);
    mfma16<4>(aF, bF, acc);
    __builtin_amdgcn_s_setprio(0);
    __builtin_amdgcn_sched_barrier(0);
    BARRIER();
  }

  const float scale = 0.08838834764831845f;   // 1/sqrt(128)
  const int r0 = lq * 4;
#pragma unroll
  for (int mi = 0; mi < 8; ++mi)
#pragma unroll
    for (int ni = 0; ni < 4; ++ni)
#pragma unroll
      for (int r = 0; r < 4; ++r) {
        const int gm = m0 + wm * 128 + mi * 16 + r0 + r;
        const int gn = n0 + wn * 64 + ni * 16 + fr;
        outp[(size_t)gm * 1024 + gn] = f2h(acc[mi][ni][r] * scale);
      }
#undef QSTAGE
#undef QLDA
#undef QLDB
}

// ---------------------------------------------------------------------------
// Row softmax, in place, causal-trimmed: only cols < ((q>>8)+1)*256 touched.
// ---------------------------------------------------------------------------
__global__ __launch_bounds__(256) void softmax_rows(unsigned short* __restrict__ s) {
  const int row = blockIdx.x, tid = threadIdx.x;
  const int lane = tid & 63, wave = tid >> 6;
  const int qv = row & 1023;
  const int nact = ((qv >> 8) + 1) << 8;
  unsigned short* r = s + (size_t)row * 1024;
  const int col = tid * 4;
  const bool act = (col < nact);
  float v[4];
  if (act) {
    u16x4 raw = *reinterpret_cast<const u16x4*>(r + col);
#pragma unroll
    for (int j = 0; j < 4; ++j)
      v[j] = (col + j <= qv) ? h2f(((unsigned short*)&raw)[j]) : -1e30f;
  } else {
#pragma unroll
    for (int j = 0; j < 4; ++j) v[j] = -1e30f;
  }
  float mx = fmaxf(fmaxf(v[0], v[1]), fmaxf(v[2], v[3]));
#pragma unroll
  for (int off = 1; off < 64; off <<= 1) mx = fmaxf(mx, __shfl_xor(mx, off, 64));
  __shared__ float redm[4], reds[4];
  if (lane == 0) redm[wave] = mx;
  __syncthreads();
  const float M = fmaxf(fmaxf(redm[0], redm[1]), fmaxf(redm[2], redm[3]));
  float e[4], ts = 0.f;
#pragma unroll
  for (int j = 0; j < 4; ++j) {
    e[j] = (act && col + j <= qv) ? __expf(v[j] - M) : 0.f;
    ts += e[j];
  }
#pragma unroll
  for (int off = 1; off < 64; off <<= 1) ts += __shfl_xor(ts, off, 64);
  if (lane == 0) reds[wave] = ts;
  __syncthreads();
  const float inv = 1.f / (reds[0] + reds[1] + reds[2] + reds[3]);
  if (act) {
    u16x4 o;
    o.x = f2bf(e[0] * inv); o.y = f2bf(e[1] * inv);
    o.z = f2bf(e[2] * inv); o.w = f2bf(e[3] * inv);
    *reinterpret_cast<u16x4*>(r + col) = o;
  }
}

// ---------------------------------------------------------------------------
// PV GEMM: per plane z=(b,h): O[q][d] = P[q][kv] * V^T[d][kv]^T.
// BM=256, BN=64, BK=64, 4 waves. Causal: NT = by*4+4. Grid (2, 4, 32).
// ---------------------------------------------------------------------------
__global__ __launch_bounds__(256, 2) void gemm_pv(
    const unsigned short* __restrict__ p, const unsigned short* __restrict__ vt,
    unsigned short* __restrict__ ao) {
  __shared__ unsigned short lds[40960];
  const int tid = threadIdx.x, lane = tid & 63, wave = tid >> 6;
  const int fr = lane & 15, lq = lane >> 4;
  const int bxn = blockIdx.x, by = blockIdx.y, z = blockIdx.z;
  const int b = z >> 4, h = z & 15, kvh = h >> 2;
  const int m0p = by * 256, n0 = bxn * 64;
  const int NT = by * 4 + 4;

  const unsigned short* A = p + (size_t)z * 1048576 + (size_t)m0p * 1024;
  const unsigned short* W =
      vt + ((size_t)(b * 4 + kvh) * 128 + n0) * 1024;

#define PVSTAGE(tt_, c_)                                                      \
  do {                                                                        \
    _Pragma("unroll")                                                         \
    for (int j = 0; j < 8; ++j) {                                             \
      const int u = wave * 512 + j * 64 + lane;                               \
      const int rw = u >> 3;                                                  \
      gload_lds16(A + (size_t)rw * 1024 + (((u & 7) ^ (rw & 7)) << 3) +       \
                      (size_t)(tt_)*64,                                       \
                  &lds[(c_)*20480 + wave * 4096 + j * 512]);                  \
    }                                                                         \
    _Pragma("unroll")                                                         \
    for (int j = 0; j < 2; ++j) {                                             \
      const int u = wave * 128 + j * 64 + lane;                               \
      const int rw = u >> 3;                                                  \
      gload_lds16(W + (size_t)rw * 1024 + (((u & 7) ^ (rw & 7)) << 3) +       \
                      (size_t)(tt_)*64,                                       \
                  &lds[(c_)*20480 + 16384 + wave * 1024 + j * 512]);          \
    }                                                                         \
  } while (0)

  const int e0 = lq ^ (fr & 7);
#define PVLDA(mi_, ks_, c_)                                                   \
  (*reinterpret_cast<const bf16x8*>(                                          \
      &lds[(c_)*20480 + (wave * 64 + (mi_)*16 + fr) * 64 +                    \
           ((e0 ^ ((ks_)*4)) << 3)]))
#define PVLDB(ni_, ks_, c_)                                                   \
  (*reinterpret_cast<const bf16x8*>(                                          \
      &lds[(c_)*20480 + 16384 + ((ni_)*16 + fr) * 64 +                        \
           ((e0 ^ ((ks_)*4)) << 3)]))

  f32x4 acc[4][4] = {};
  bf16x8 aF[4], bF[4];

  PVSTAGE(0, 0);

  for (int t = 0; t < NT; ++t) {
    const int c = t & 1;
    if (t + 1 < NT) {
      PVSTAGE(t + 1, c ^ 1);
      asm volatile("s_waitcnt vmcnt(10)" ::: "memory");
    } else {
      asm volatile("s_waitcnt vmcnt(0)" ::: "memory");
    }
    BARRIER();
#pragma unroll
    for (int ks = 0; ks < 2; ++ks) {
      bF[0] = PVLDB(0, ks, c); bF[1] = PVLDB(1, ks, c);
      bF[2] = PVLDB(2, ks, c); bF[3] = PVLDB(3, ks, c);
      aF[0] = PVLDA(0, ks, c); aF[1] = PVLDA(1, ks, c);
      aF[2] = PVLDA(2, ks, c); aF[3] = PVLDA(3, ks, c);
      BARRIER();
      __builtin_amdgcn_s_setprio(1);
#pragma unroll
      for (int ni = 0; ni < 4; ++ni)
#pragma unroll
        for (int mi = 0; mi < 4; ++mi)
          acc[mi][ni] = __builtin_amdgcn_mfma_f32_16x16x32_bf16(
              aF[mi], bF[ni], acc[mi][ni], 0, 0, 0);
      __builtin_amdgcn_s_setprio(0);
      __builtin_amdgcn_sched_barrier(0);
      BARRIER();
    }
  }

  const int r0 = lq * 4;
#pragma unroll
  for (int mi = 0; mi < 4; ++mi)
#pragma unroll
    for (int ni = 0; ni < 4; ++ni)
#pragma unroll
      for (int r = 0; r < 4; ++r) {
        const int gm = m0p + wave * 64 + mi * 16 + r0 + r;
        const int gn = n0 + ni * 16 + fr;
        ao[(size_t)(b * 1024 + gm) * HIDDIM + h * HDIM + gn] =
            f2bf(acc[mi][ni][r]);
      }
#undef PVSTAGE
#undef PVLDA
#undef PVLDB
}

// ---------------------------------------------------------------------------
// QKV split-K2 reduce (bf16 partials) + bias + RoPE + V-transpose.
// ---------------------------------------------------------------------------
__global__ __launch_bounds__(256) void reduce_qkv(
    const unsigned short* __restrict__ p, const float* __restrict__ qb,
    const float* __restrict__ kb, const float* __restrict__ vb,
    const float* __restrict__ cosb, const float* __restrict__ sinb,
    unsigned short* __restrict__ qo, unsigned short* __restrict__ ko,
    unsigned short* __restrict__ vto) {
  const int i = blockIdx.x * 256 + threadIdx.x;   // < 1,572,864
  const int row = i / 768, c4 = (i - row * 768) * 4;
  const unsigned short* p0 = p + (size_t)row * 3072;
  const unsigned short* p1 = p + 6291456 + (size_t)row * 3072;
  const u16x4 a0 = *reinterpret_cast<const u16x4*>(p0 + c4);
  const u16x4 a1 = *reinterpret_cast<const u16x4*>(p1 + c4);
  f32x4 s;
  s.x = bf2f(a0.x) + bf2f(a1.x); s.y = bf2f(a0.y) + bf2f(a1.y);
  s.z = bf2f(a0.z) + bf2f(a1.z); s.w = bf2f(a0.w) + bf2f(a1.w);
  if (c4 < 2560) {
    const float* bias; unsigned short* out; int d, ldo;
    if (c4 < 2048) { bias = qb; out = qo; d = c4;        ldo = HIDDIM; }
    else           { bias = kb; out = ko; d = c4 - 2048; ldo = KVDIM; }
    const int dd = d & 127;
    const bool lohalf = (dd < 64);
    const int pc = lohalf ? c4 + 64 : c4 - 64;
    const int pd = lohalf ? d + 64 : d - 64;
    const u16x4 b0 = *reinterpret_cast<const u16x4*>(p0 + pc);
    const u16x4 b1 = *reinterpret_cast<const u16x4*>(p1 + pc);
    f32x4 sp;
    sp.x = bf2f(b0.x) + bf2f(b1.x); sp.y = bf2f(b0.y) + bf2f(b1.y);
    sp.z = bf2f(b0.z) + bf2f(b1.z); sp.w = bf2f(b0.w) + bf2f(b1.w);
    const f32x4 bv = *reinterpret_cast<const f32x4*>(bias + d);
    const f32x4 bp = *reinterpret_cast<const f32x4*>(bias + pd);
    const f32x4 cv = *reinterpret_cast<const f32x4*>(cosb + (size_t)row * 128 + dd);
    const f32x4 sv = *reinterpret_cast<const f32x4*>(sinb + (size_t)row * 128 + dd);
    const f32x4 xv = s + bv, pv = sp + bp;
    f32x4 o;
    if (lohalf) o = xv * cv - pv * sv;
    else        o = xv * cv + pv * sv;
    u16x4 ob;
    ob.x = f2bf(o.x); ob.y = f2bf(o.y); ob.z = f2bf(o.z); ob.w = f2bf(o.w);
    *reinterpret_cast<u16x4*>(out + (size_t)row * ldo + d) = ob;
  } else {
    const int d = c4 - 2560;
    const int kvh = d >> 7, dd = d & 127;
    const int b = row >> 10, t = row & 1023;
    const f32x4 bv = *reinterpret_cast<const f32x4*>(vb + d);
    const f32x4 o = s + bv;
    unsigned short* vr =
        vto + ((size_t)(b * 4 + kvh) * 128 + dd) * 1024 + t;
    vr[0] = f2bf(o.x); vr[1024] = f2bf(o.y);
    vr[2048] = f2bf(o.z); vr[3072] = f2bf(o.w);
  }
}

// ---------------------------------------------------------------------------
extern "C" void kernel_launch(void* const* d_in, const int* in_sizes, int n_in,
                              void* d_out, int out_size, void* d_ws,
                              size_t ws_size, hipStream_t stream) {
  (void)in_sizes; (void)n_in; (void)out_size; (void)ws_size;
  const float* hidden = (const float*)d_in[0];
  const float* cosb  = (const float*)d_in[1];
  const float* sinb  = (const float*)d_in[2];
  const float* qw    = (const float*)d_in[3];
  const float* qbias = (const float*)d_in[4];
  const float* kw    = (const float*)d_in[5];
  const float* kbias = (const float*)d_in[6];
  const float* vw    = (const float*)d_in[7];
  const float* vbias = (const float*)d_in[8];
  const float* ow    = (const float*)d_in[9];
  const float* gw    = (const float*)d_in[10];
  const float* uw    = (const float*)d_in[11];
  const float* dw    = (const float*)d_in[12];
  const float* ln1   = (const float*)d_in[13];
  const float* ln2   = (const float*)d_in[14];
  const float* normw = (const float*)d_in[15];

  char* ws = (char*)d_ws;
  float* x               = (float*)ws;                          // 0        16.8M
  unsigned short* hbuf   = (unsigned short*)(ws + 16777216);    // 16.8M     8.4M
  unsigned short* qbuf   = (unsigned short*)(ws + 25165824);    // 25.2M     8.4M
  unsigned short* kbuf   = (unsigned short*)(ws + 33554432);    // 33.6M     2.1M
  unsigned short* vtbuf  = (unsigned short*)(ws + 35651584);    // 35.7M     2.1M
  unsigned short* aobuf  = (unsigned short*)(ws + 39845888);    // 39.8M     8.4M
  unsigned short* actbuf = (unsigned short*)(ws + 71303168);    // 71.3M    23.1M
  unsigned short* wcvt   = (unsigned short*)(ws + 94371840);    // 94.4M    23.1M
  // total footprint: 117,440,512 bytes
  //
  // Overlays (regions dead at time-of-use, stream-serialized):
  //  - pbQKV: 2 bf16 planes [2048][3072] at 37.75M (25.2 MB, over gap+aobuf+)
  unsigned short* pbQKV = (unsigned short*)(ws + 37748736);
  //  - sbuf: 32 x [1024][1024] u16 S/P planes at 48.2M (67 MB, -> 115.3M)
  unsigned short* sbuf = (unsigned short*)(ws + 48234496);
  //  - pbO: 2 bf16 planes [2048][2048] at 48.2M (16.8 MB; sbuf dead post-PV)
  unsigned short* pbO = (unsigned short*)(ws + 48234496);
  //  - wgu: [11264][2048] bf16 at 25.2M (46.1 MB -> exactly 71.3M=actbuf)
  unsigned short* wgu = (unsigned short*)(ws + 25165824);
  //  - pbD: 3 bf16 planes [2048][2048] at 25.2M (25.2 MB; wgu dead post-GU)
  unsigned short* pbD = (unsigned short*)(ws + 25165824);

  unsigned short* wq16 = wcvt;                 // [3072][2048] bf16
  unsigned short* wk16 = wcvt + 4194304;
  unsigned short* wv16 = wcvt + 5242880;
  unsigned short* ow16 = wcvt;                 // reused after QKV GEMM

  hipMemcpyAsync(x, hidden, (size_t)NTOK * HIDDIM * 4,
                 hipMemcpyDeviceToDevice, stream);
  rmsnorm_kernel<0><<<NTOK, 256, 0, stream>>>(x, ln1, hbuf);   // layer-0 ln1

  for (int l = 0; l < 4; ++l) {
    const float* qw_l = qw + (size_t)l * 2048 * 2048;
    const float* qb_l = qbias + (size_t)l * 2048;
    const float* kw_l = kw + (size_t)l * 512 * 2048;
    const float* kb_l = kbias + (size_t)l * 512;
    const float* vw_l = vw + (size_t)l * 512 * 2048;
    const float* vb_l = vbias + (size_t)l * 512;
    const float* ow_l = ow + (size_t)l * 2048 * 2048;
    const float* gw_l = gw + (size_t)l * 5632 * 2048;
    const float* uw_l = uw + (size_t)l * 5632 * 2048;
    const float* dw_l = dw + (size_t)l * 2048 * 5632;

    cvt_kernel<<<2048, 256, 0, stream>>>(qw_l, wq16, 524288);
    cvt_kernel<<<512, 256, 0, stream>>>(kw_l, wk16, 131072);
    cvt_kernel<<<512, 256, 0, stream>>>(vw_l, wv16, 131072);
    gemm8p<<<dim3(12, 8, 2), 512, 0, stream>>>(
        hbuf, wcvt, pbQKV, 2048, 3072, 16, 32, (size_t)6291456);
    reduce_qkv<<<6144, 256, 0, stream>>>(pbQKV, qb_l, kb_l, vb_l, cosb, sinb,
                                         qbuf, kbuf, vtbuf);

    gemm_qk<<<dim3(4, 4, 32), 512, 0, stream>>>(qbuf, kbuf, sbuf);
    softmax_rows<<<32768, 256, 0, stream>>>(sbuf);
    gemm_pv<<<dim3(2, 4, 32), 256, 0, stream>>>(sbuf, vtbuf, aobuf);

    cvt_kernel<<<2048, 256, 0, stream>>>(ow_l, ow16, 524288);
    gemm8p<<<dim3(8, 8, 2), 512, 0, stream>>>(
        aobuf, ow16, pbO, 2048, 2048, 16, 32, (size_t)4194304);
    reduce_rms<2, 0><<<NTOK, 256, 0, stream>>>(x, pbO, (size_t)4194304,
                                               ln2 + l * 2048, hbuf);

    cvt_gu<<<11264, 256, 0, stream>>>(gw_l, uw_l, wgu);
    gemm_gu<<<dim3(44, 8), 512, 0, stream>>>(hbuf, wgu, actbuf);

    cvt_kernel<<<5632, 256, 0, stream>>>(dw_l, wcvt, 1441792);
    gemm8p<<<dim3(8, 8, 3), 512, 0, stream>>>(
        actbuf, wcvt, pbD, 5632, 2048, 30, 88, (size_t)4194304);
    if (l < 3) {
      reduce_rms<3, 0><<<NTOK, 256, 0, stream>>>(
          x, pbD, (size_t)4194304, ln1 + (l + 1) * 2048, hbuf);
    } else {
      reduce_rms<3, 1><<<NTOK, 256, 0, stream>>>(x, pbD, (size_t)4194304,
                                                 normw, d_out);
    }
  }
}